// Round 1
// 524.467 us; speedup vs baseline: 1.0246x; 1.0246x over previous
//
#include <hip/hip_runtime.h>
#include <math.h>

// ---------------------------------------------------------------------------
// TimeMix (RWKV-6 vision block) — round 10: k_wkv_intra phase-2 re-blocking.
// 4 rows x 4 chans (float4) per thread: main-loop LDS instrs 576->192/thread,
// GN shuffles 192->32/thread (16-lane subgroup reduce). fp32 kept everywhere
// in the recurrence (no new precision risk). B=8, T=1024, C=768, H=12.
// ---------------------------------------------------------------------------

#define EPI_NONE 0
#define EPI_TANH 1
#define EPI_RELU 2
#define EPI_BIAS 3

#define LPAD 68   // LDS row stride (floats) for 64-wide chunk tiles

typedef float f32x4 __attribute__((ext_vector_type(4)));
typedef __bf16 bf16x8 __attribute__((ext_vector_type(8)));

__device__ __forceinline__ ushort f2bf(float x) {
  unsigned u = __float_as_uint(x);
  return (ushort)((u + 0x7fffu + ((u >> 16) & 1u)) >> 16);
}

#define GLDS16(gp, lp)                                                   \
  __builtin_amdgcn_global_load_lds(                                      \
      (const __attribute__((address_space(1))) void*)(gp),               \
      (__attribute__((address_space(3))) void*)(lp), 16, 0, 0)

// ---------------------------------------------------------------- qshift ---
__global__ __launch_bounds__(256) void k_qshift(
    const float* __restrict__ x, const float* __restrict__ maa_x,
    float* __restrict__ xx, ushort* __restrict__ xxx_bf,
    int B, int T, int C, int ph, int pw) {
  long idx = (long)blockIdx.x * blockDim.x + threadIdx.x;
  long total = (long)B * T * C;
  if (idx >= total) return;
  int c = (int)(idx % C);
  long bt = idx / C;
  int t = (int)(bt % T);
  int quarter = (c & 63) >> 4;
  int hh = t / pw;
  int ww = t - hh * pw;
  long rowbase = (bt - t) * C;
  float sval = 0.f;
  int st = -1;
  if (quarter == 0)      { if (ww >= 1)      st = t - 1;  }
  else if (quarter == 1) { if (ww < pw - 1)  st = t + 1;  }
  else if (quarter == 2) { if (hh >= 1)      st = t - pw; }
  else                   { if (hh < ph - 1)  st = t + pw; }
  if (st >= 0) sval = x[rowbase + (long)st * C + c];
  float xval = x[idx];
  float d = sval - xval;
  xx[idx] = d;
  xxx_bf[idx] = f2bf(xval + d * maa_x[c]);
}

// ------------------------------------- maa_w1 transpose+convert to bf16 ----
__global__ __launch_bounds__(256) void k_w1t(
    const float* __restrict__ w1, ushort* __restrict__ out) {
  int n = blockIdx.y;
  int k = blockIdx.x * 256 + threadIdx.x;
  float v = (n < 160) ? w1[(size_t)k * 160 + n] : 0.f;
  out[(size_t)n * 768 + k] = f2bf(v);
}

// -------------------------- dec_w1 / dec_w2 transpose+convert to bf16 ------
__global__ __launch_bounds__(256) void k_decT(
    const float* __restrict__ w1, const float* __restrict__ w2,
    ushort* __restrict__ w1dT, ushort* __restrict__ w2dT) {
  int idx = blockIdx.x * 256 + threadIdx.x;
  if (idx < 128 * 768) {
    int n = idx / 768, k = idx - n * 768;
    float v = (n < 64) ? w1[(size_t)k * 64 + n] : 0.f;
    w1dT[idx] = f2bf(v);
  } else {
    int j = idx - 128 * 768;
    int n = j >> 6, k = j & 63;
    w2dT[j] = f2bf(w2[(size_t)k * 768 + n]);
  }
}

// ---------------------------------------------- mix5 fused GEMM+epilogue ---
__global__ __launch_bounds__(256) void k_mix5f(
    const float* __restrict__ t5, const float* __restrict__ maa_w2,
    const float* __restrict__ x, const float* __restrict__ xx,
    const float* __restrict__ maa_w, const float* __restrict__ maa_k,
    const float* __restrict__ maa_v, const float* __restrict__ maa_r,
    const float* __restrict__ maa_g,
    ushort* __restrict__ xw, ushort* __restrict__ xk, ushort* __restrict__ xvb,
    ushort* __restrict__ xr, ushort* __restrict__ xg, int C) {
  __shared__ float As[64][36];
  __shared__ float Bs[32][64];
  int tid = threadIdx.x;
  int m0 = blockIdx.y * 64, n0 = blockIdx.x * 64;
  int tx = tid & 15, ty = tid >> 4;
  int cb = n0 + tx * 4;
  float4 xv4[4], dd4[4];
#pragma unroll
  for (int i = 0; i < 4; i++) {
    size_t off = (size_t)(m0 + ty * 4 + i) * C + cb;
    xv4[i] = *(const float4*)(x + off);
    dd4[i] = *(const float4*)(xx + off);
  }

#pragma unroll
  for (int f = 0; f < 5; f++) {
    {
      int k4 = (tid & 7) * 4;
      int row = tid >> 3;
      const float* src = t5 + (size_t)(m0 + row) * 160 + f * 32 + k4;
      float4 v0 = *(const float4*)src;
      float4 v1 = *(const float4*)(src + 32 * 160);
      *(float4*)(&As[row][k4]) = v0;
      *(float4*)(&As[row + 32][k4]) = v1;
    }
    {
      int col = (tid & 15) * 4, kk = tid >> 4;
      const float* src = maa_w2 + (size_t)(f * 32 + kk) * C + n0 + col;
      *(float4*)(&Bs[kk][col]) = *(const float4*)src;
      *(float4*)(&Bs[kk + 16][col]) = *(const float4*)(src + (size_t)16 * C);
    }
    __syncthreads();
    float acc[4][4];
#pragma unroll
    for (int i = 0; i < 4; i++)
#pragma unroll
      for (int j = 0; j < 4; j++) acc[i][j] = 0.f;
#pragma unroll
    for (int kk = 0; kk < 32; kk++) {
      float4 b4 = *(const float4*)(&Bs[kk][tx * 4]);
#pragma unroll
      for (int i = 0; i < 4; i++) {
        float a = As[ty * 4 + i][kk];
        acc[i][0] = fmaf(a, b4.x, acc[i][0]);
        acc[i][1] = fmaf(a, b4.y, acc[i][1]);
        acc[i][2] = fmaf(a, b4.z, acc[i][2]);
        acc[i][3] = fmaf(a, b4.w, acc[i][3]);
      }
    }
    __syncthreads();
    const float* maa_f = (f == 0) ? maa_w : (f == 1) ? maa_k
                        : (f == 2) ? maa_v : (f == 3) ? maa_r : maa_g;
    ushort* dst = (f == 0) ? xw : (f == 1) ? xk
                 : (f == 2) ? xvb : (f == 3) ? xr : xg;
    float4 mf = *(const float4*)(maa_f + cb);
#pragma unroll
    for (int i = 0; i < 4; i++) {
      size_t off = (size_t)(m0 + ty * 4 + i) * C + cb;
      ushort4 ob;
      ob.x = f2bf(xv4[i].x + dd4[i].x * (mf.x + acc[i][0]));
      ob.y = f2bf(xv4[i].y + dd4[i].y * (mf.y + acc[i][1]));
      ob.z = f2bf(xv4[i].z + dd4[i].z * (mf.z + acc[i][2]));
      ob.w = f2bf(xv4[i].w + dd4[i].w * (mf.w + acc[i][3]));
      *(ushort4*)(dst + off) = ob;
    }
  }
}

// -------------------------------------------- fp32 -> bf16 cvt (5 arrays) --
__global__ __launch_bounds__(256) void k_cvt5(
    const float* __restrict__ s0, const float* __restrict__ s1,
    const float* __restrict__ s2, const float* __restrict__ s3,
    const float* __restrict__ s4,
    ushort* __restrict__ d0, ushort* __restrict__ d1,
    ushort* __restrict__ d2, ushort* __restrict__ d3,
    ushort* __restrict__ d4, int n) {
  const float* s;
  ushort* d;
  switch (blockIdx.y) {
    case 0: s = s0; d = d0; break;
    case 1: s = s1; d = d1; break;
    case 2: s = s2; d = d2; break;
    case 3: s = s3; d = d3; break;
    default: s = s4; d = d4; break;
  }
  int i = (blockIdx.x * 256 + threadIdx.x) * 4;
  if (i >= n) return;
  float4 v = *(const float4*)(s + i);
  ushort4 o;
  o.x = f2bf(v.x); o.y = f2bf(v.y); o.z = f2bf(v.z); o.w = f2bf(v.w);
  *(ushort4*)(d + i) = o;
}

// ----------------------------------------------------- bf16 MFMA GEMM ------
template <int EPI, bool NMASK, bool OBF16>
__global__ __launch_bounds__(256) void k_gemm_bf(
    const ushort* __restrict__ A, const ushort* __restrict__ W,
    const float* __restrict__ bias, void* __restrict__ Cm,
    int M, int N, int K) {
  __shared__ ushort Al[128 * 32];
  __shared__ ushort Bl[128 * 32];
  int tid = threadIdx.x;
  int m0 = blockIdx.y * 128, n0 = blockIdx.x * 128;
  int lane = tid & 63, wave = tid >> 6;
  int wm = (wave >> 1) * 64, wn = (wave & 1) * 64;
  int lm = lane & 15, lk = (lane >> 4) * 8;
  f32x4 acc[4][4];
#pragma unroll
  for (int i = 0; i < 4; i++)
#pragma unroll
    for (int j = 0; j < 4; j++) acc[i][j] = (f32x4){0.f, 0.f, 0.f, 0.f};

  int arow = tid >> 2, achunk = (tid & 3) * 8;
  const ushort* Ag = A + (size_t)(m0 + arow) * K + achunk;
  const ushort* Wg = W + (size_t)(n0 + arow) * K + achunk;
  ushort* Ald = Al + tid * 8;
  ushort* Bld = Bl + tid * 8;

  for (int k0 = 0; k0 < K; k0 += 32) {
    GLDS16(Ag + k0, Ald);
    GLDS16(Ag + (size_t)64 * K + k0, Ald + 2048);
    GLDS16(Wg + k0, Bld);
    GLDS16(Wg + (size_t)64 * K + k0, Bld + 2048);
    __syncthreads();
    bf16x8 af[4], bf[4];
#pragma unroll
    for (int i = 0; i < 4; i++)
      af[i] = *(const bf16x8*)&Al[(wm + i * 16 + lm) * 32 + lk];
#pragma unroll
    for (int j = 0; j < 4; j++)
      bf[j] = *(const bf16x8*)&Bl[(wn + j * 16 + lm) * 32 + lk];
#pragma unroll
    for (int i = 0; i < 4; i++)
#pragma unroll
      for (int j = 0; j < 4; j++)
        acc[i][j] = __builtin_amdgcn_mfma_f32_16x16x32_bf16(
            af[i], bf[j], acc[i][j], 0, 0, 0);
    __syncthreads();
  }
  int rq = (lane >> 4) * 4;
#pragma unroll
  for (int i = 0; i < 4; i++) {
#pragma unroll
    for (int j = 0; j < 4; j++) {
      int gn = n0 + wn + j * 16 + lm;
      if (NMASK && gn >= N) continue;
      float bv = (EPI == EPI_BIAS) ? bias[gn] : 0.f;
#pragma unroll
      for (int q = 0; q < 4; q++) {
        int gm = m0 + wm + i * 16 + rq + q;
        float val = acc[i][j][q];
        if (EPI == EPI_BIAS) val += bv;
        if (EPI == EPI_RELU) val = fmaxf(val, 0.f);
        if (EPI == EPI_TANH) val = tanhf(val);
        if (OBF16) ((ushort*)Cm)[(size_t)gm * N + gn] = f2bf(val);
        else       ((float*)Cm)[(size_t)gm * N + gn] = val;
      }
    }
  }
}

// --------------------------------- batched 4-projection bf16 MFMA GEMM -----
__global__ __launch_bounds__(256) void k_proj4(
    const ushort* __restrict__ A0, const ushort* __restrict__ A1,
    const ushort* __restrict__ A2, const ushort* __restrict__ A3,
    const ushort* __restrict__ W0, const ushort* __restrict__ W1,
    const ushort* __restrict__ W2, const ushort* __restrict__ W3,
    float* __restrict__ C0, float* __restrict__ C1,
    float* __restrict__ C2, float* __restrict__ C3,
    int M, int N, int K) {
  int z = blockIdx.z;
  const ushort* A = (z == 0) ? A0 : (z == 1) ? A1 : (z == 2) ? A2 : A3;
  const ushort* W = (z == 0) ? W0 : (z == 1) ? W1 : (z == 2) ? W2 : W3;
  float* Cm       = (z == 0) ? C0 : (z == 1) ? C1 : (z == 2) ? C2 : C3;
  __shared__ ushort Al[128 * 32];
  __shared__ ushort Bl[128 * 32];
  int tid = threadIdx.x;
  int m0 = blockIdx.y * 128, n0 = blockIdx.x * 128;
  int lane = tid & 63, wave = tid >> 6;
  int wm = (wave >> 1) * 64, wn = (wave & 1) * 64;
  int lm = lane & 15, lk = (lane >> 4) * 8;
  f32x4 acc[4][4];
#pragma unroll
  for (int i = 0; i < 4; i++)
#pragma unroll
    for (int j = 0; j < 4; j++) acc[i][j] = (f32x4){0.f, 0.f, 0.f, 0.f};

  int arow = tid >> 2, achunk = (tid & 3) * 8;
  const ushort* Ag = A + (size_t)(m0 + arow) * K + achunk;
  const ushort* Wg = W + (size_t)(n0 + arow) * K + achunk;
  ushort* Ald = Al + tid * 8;
  ushort* Bld = Bl + tid * 8;

  for (int k0 = 0; k0 < K; k0 += 32) {
    GLDS16(Ag + k0, Ald);
    GLDS16(Ag + (size_t)64 * K + k0, Ald + 2048);
    GLDS16(Wg + k0, Bld);
    GLDS16(Wg + (size_t)64 * K + k0, Bld + 2048);
    __syncthreads();
    bf16x8 af[4], bf[4];
#pragma unroll
    for (int i = 0; i < 4; i++)
      af[i] = *(const bf16x8*)&Al[(wm + i * 16 + lm) * 32 + lk];
#pragma unroll
    for (int j = 0; j < 4; j++)
      bf[j] = *(const bf16x8*)&Bl[(wn + j * 16 + lm) * 32 + lk];
#pragma unroll
    for (int i = 0; i < 4; i++)
#pragma unroll
      for (int j = 0; j < 4; j++)
        acc[i][j] = __builtin_amdgcn_mfma_f32_16x16x32_bf16(
            af[i], bf[j], acc[i][j], 0, 0, 0);
    __syncthreads();
  }
  bool relu = (z == 3);
  int rq = (lane >> 4) * 4;
#pragma unroll
  for (int i = 0; i < 4; i++) {
#pragma unroll
    for (int j = 0; j < 4; j++) {
      int gn = n0 + wn + j * 16 + lm;
#pragma unroll
      for (int q = 0; q < 4; q++) {
        int gm = m0 + wm + i * 16 + rq + q;
        float val = acc[i][j][q];
        if (relu) val = fmaxf(val, 0.f);
        Cm[(size_t)gm * N + gn] = val;
      }
    }
  }
}

// ------------------------------------------------- chunked WKV: phase pre --
__global__ __launch_bounds__(64) void k_wkv_pre(
    const float* __restrict__ r, const float* __restrict__ k,
    const float* __restrict__ w, const float* __restrict__ u,
    float* __restrict__ rt, float* __restrict__ kt,
    float* __restrict__ aL, float* __restrict__ pdiag,
    int B, int T, int C, int H, int L) {
  int nch = T / L;
  int blk = blockIdx.x;
  int bh = blk / nch, c = blk - bh * nch;
  int b = bh / H, h = bh - b * H;
  int j = threadIdx.x;
  float uj = u[h * 64 + j];
  float cum = 0.f;
  long base = ((long)b * T + (long)c * L) * C + h * 64 + j;
  for (int tau = 0; tau < L; tau++) {
    long off = base + (long)tau * C;
    float wv = w[off];
    float rv = r[off];
    float kv = k[off];
    float e = expf(wv);
    rt[off] = rv * expf(-cum);
    cum += e;
    kt[off] = kv * expf(cum);
    float pd = rv * uj * kv;
#pragma unroll
    for (int o = 32; o >= 1; o >>= 1) pd += __shfl_xor(pd, o, 64);
    if (j == 0) pdiag[(long)bh * T + c * L + tau] = pd;
  }
  aL[((long)bh * nch + c) * 64 + j] = expf(-cum);
}

// --------------------------------------- chunked WKV: per-chunk KV outer ---
__global__ __launch_bounds__(256) void k_wkv_kv(
    const float* __restrict__ kt, const float* __restrict__ v,
    float* __restrict__ kvb, int B, int T, int C, int H, int L) {
  int nch = T / L;
  int blk = blockIdx.x;
  int bh = blk / nch, c = blk - bh * nch;
  int b = bh / H, h = bh - b * H;
  __shared__ float Ks[64 * LPAD];
  __shared__ float Vs[64 * LPAD];
  int tid = threadIdx.x;
  int lane = tid & 63, jg = tid >> 6;
  long cbase = ((long)b * T + (long)c * L) * C + h * 64;
#pragma unroll
  for (int q = 0; q < 4; q++) {
    int idx = tid + q * 256;
    int row = idx >> 4, col = (idx & 15) * 4;
    long g = cbase + (long)row * C + col;
    *(float4*)(Ks + row * LPAD + col) = *(const float4*)(kt + g);
    *(float4*)(Vs + row * LPAD + col) = *(const float4*)(v + g);
  }
  __syncthreads();
  float acc[16];
#pragma unroll
  for (int q = 0; q < 16; q++) acc[q] = 0.f;
  for (int s = 0; s < 64; s++) {
    float vi = Vs[s * LPAD + lane];
#pragma unroll
    for (int q4 = 0; q4 < 4; q4++) {
      float4 kk = *(const float4*)(Ks + s * LPAD + jg * 16 + q4 * 4);
      acc[q4 * 4 + 0] = fmaf(kk.x, vi, acc[q4 * 4 + 0]);
      acc[q4 * 4 + 1] = fmaf(kk.y, vi, acc[q4 * 4 + 1]);
      acc[q4 * 4 + 2] = fmaf(kk.z, vi, acc[q4 * 4 + 2]);
      acc[q4 * 4 + 3] = fmaf(kk.w, vi, acc[q4 * 4 + 3]);
    }
  }
  float* out = kvb + ((long)bh * nch + c) * 4096;
#pragma unroll
  for (int q = 0; q < 16; q++) out[(jg * 16 + q) * 64 + lane] = acc[q];
}

// ---------------------------------------- chunked WKV: state prefix scan ---
__global__ __launch_bounds__(256) void k_wkv_scan(
    const float* __restrict__ kvb, const float* __restrict__ aL,
    float* __restrict__ Scb, int nch) {
  int bh = blockIdx.x;
  int tid = threadIdx.x;
  float S[16];
#pragma unroll
  for (int q = 0; q < 16; q++) S[q] = 0.f;
  for (int c = 0; c < nch; c++) {
    const float* kv = kvb + ((long)bh * nch + c) * 4096;
    float* sc = Scb + ((long)bh * nch + c) * 4096;
    const float* aLc = aL + ((long)bh * nch + c) * 64;
#pragma unroll
    for (int q = 0; q < 16; q++) {
      int e = q * 256 + tid;
      sc[e] = S[q];
      S[q] = aLc[e >> 6] * (S[q] + kv[e]);
    }
  }
}

// ------------- chunked WKV: intra + inter + groupnorm*gate (fused) ---------
// y = mask(Rt Kt^T + diag) @ V + Rt @ S_prev; GN over head channels; gate.
// Phase 2 re-blocked: each thread owns 4 rows x 4 chans (float4 acc), so the
// contraction reads 4 b128/iter (P^T,Rt^T multicast + Vs + S_prev global)
// instead of 10 mem ops, and GN reduces over a 16-lane subgroup (4-step
// shfl_xor) with 4 chans pre-reduced in-register. All named regs / static
// indices (no scratch). fp32 throughout.
__global__ __launch_bounds__(256, 3) void k_wkv_intra(
    const float* __restrict__ rt, const float* __restrict__ kt,
    const float* __restrict__ v, const float* __restrict__ pdiag,
    const float* __restrict__ Scb, const float* __restrict__ g,
    const float* __restrict__ ln_w, const float* __restrict__ ln_b,
    ushort* __restrict__ z, int B, int T, int C, int H, int L) {
  int nch = T / L;
  int blk = blockIdx.x;
  int bh = blk / nch, c = blk - bh * nch;
  int b = bh / H, h = bh - b * H;
  __shared__ float RPs[64 * LPAD];   // Rt tile -> P^T
  __shared__ float Ks[64 * LPAD];    // Kt tile -> Rt^T
  __shared__ float Vs[64 * LPAD];
  int tid = threadIdx.x;
  long cbase = ((long)b * T + (long)c * L) * C + h * 64;
  const float* scp = Scb + ((long)bh * nch + c) * 4096;
#pragma unroll
  for (int q = 0; q < 4; q++) {
    int idx = tid + q * 256;
    int row = idx >> 4, col = (idx & 15) * 4;
    long g4 = cbase + (long)row * C + col;
    *(float4*)(RPs + row * LPAD + col) = *(const float4*)(rt + g4);
    *(float4*)(Ks + row * LPAD + col) = *(const float4*)(kt + g4);
    *(float4*)(Vs + row * LPAD + col) = *(const float4*)(v + g4);
  }
  __syncthreads();
  int tau = tid & 63, sg = tid >> 6;
  float4 rreg[16];
#pragma unroll
  for (int q = 0; q < 16; q++)
    rreg[q] = *(const float4*)(RPs + tau * LPAD + q * 4);
  float pd = pdiag[(long)bh * T + c * L + tau];
  __syncthreads();   // Rt reads done; RPs becomes P^T storage
#pragma unroll 2
  for (int ss = 0; ss < 16; ss++) {
    int s = sg * 16 + ss;
    float a0 = 0.f, a1 = 0.f, a2 = 0.f, a3 = 0.f;
#pragma unroll
    for (int q = 0; q < 16; q++) {
      float4 kk = *(const float4*)(Ks + s * LPAD + q * 4);
      a0 = fmaf(rreg[q].x, kk.x, a0);
      a1 = fmaf(rreg[q].y, kk.y, a1);
      a2 = fmaf(rreg[q].z, kk.z, a2);
      a3 = fmaf(rreg[q].w, kk.w, a3);
    }
    float a = (a0 + a1) + (a2 + a3);
    float val = (s < tau) ? a : (s == tau ? pd : 0.f);
    RPs[s * LPAD + tau] = val;
  }
  __syncthreads();   // Kt reads done; Ks becomes Rt^T storage
#pragma unroll
  for (int qq = 0; qq < 16; qq++) {
    const float* rr = (const float*)&rreg[sg * 4 + (qq >> 2)];
    Ks[(sg * 16 + qq) * LPAD + tau] = rr[qq & 3];
  }
  __syncthreads();
  // ---- phase 2: Y[r,c] = sum_j P^T[j][r]*V[j][c] + Rt^T[j][r]*S[j][c] ----
  int lane = tid & 63, wid = tid >> 6;
  int row0 = wid * 16 + (lane >> 4) * 4;   // 4 consecutive output rows
  int c0 = (lane & 15) * 4;                // 4 consecutive output channels
  float4 acc0 = {0.f, 0.f, 0.f, 0.f};
  float4 acc1 = {0.f, 0.f, 0.f, 0.f};
  float4 acc2 = {0.f, 0.f, 0.f, 0.f};
  float4 acc3 = {0.f, 0.f, 0.f, 0.f};
#define FMA4(A, P, V4, R, S4)                          \
  A.x = fmaf(P, V4.x, fmaf(R, S4.x, A.x));             \
  A.y = fmaf(P, V4.y, fmaf(R, S4.y, A.y));             \
  A.z = fmaf(P, V4.z, fmaf(R, S4.z, A.z));             \
  A.w = fmaf(P, V4.w, fmaf(R, S4.w, A.w));
#pragma unroll 4
  for (int j = 0; j < 64; j++) {
    float4 pp = *(const float4*)(RPs + j * LPAD + row0);   // 16-lane multicast
    float4 rr = *(const float4*)(Ks + j * LPAD + row0);    // 16-lane multicast
    float4 vv = *(const float4*)(Vs + j * LPAD + c0);      // 2-way (free)
    float4 ssv = *(const float4*)(scp + j * 64 + c0);      // 256B/wave, L1 x4
    FMA4(acc0, pp.x, vv, rr.x, ssv);
    FMA4(acc1, pp.y, vv, rr.y, ssv);
    FMA4(acc2, pp.z, vv, rr.z, ssv);
    FMA4(acc3, pp.w, vv, rr.w, ssv);
  }
#undef FMA4
  // ---- fused groupnorm (per row over this head's 64 channels) * gate ----
  float4 lw4 = *(const float4*)(ln_w + h * 64 + c0);
  float4 lb4 = *(const float4*)(ln_b + h * 64 + c0);
#define GNROW(A, m)                                                        \
  {                                                                        \
    float s1 = (A.x + A.y) + (A.z + A.w);                                  \
    s1 += __shfl_xor(s1, 1, 64);                                           \
    s1 += __shfl_xor(s1, 2, 64);                                           \
    s1 += __shfl_xor(s1, 4, 64);                                           \
    s1 += __shfl_xor(s1, 8, 64);                                           \
    float mu = s1 * (1.f / 64.f);                                          \
    float4 dd;                                                             \
    dd.x = A.x - mu; dd.y = A.y - mu; dd.z = A.z - mu; dd.w = A.w - mu;    \
    float s2 = (dd.x * dd.x + dd.y * dd.y) + (dd.z * dd.z + dd.w * dd.w);  \
    s2 += __shfl_xor(s2, 1, 64);                                           \
    s2 += __shfl_xor(s2, 2, 64);                                           \
    s2 += __shfl_xor(s2, 4, 64);                                           \
    s2 += __shfl_xor(s2, 8, 64);                                           \
    float rstd = rsqrtf(s2 * (1.f / 64.f) + 1e-5f);                        \
    long off = cbase + (long)(row0 + m) * C + c0;                          \
    float4 g4 = *(const float4*)(g + off);                                 \
    ushort4 ob;                                                            \
    ob.x = f2bf((dd.x * rstd * lw4.x + lb4.x) * g4.x);                     \
    ob.y = f2bf((dd.y * rstd * lw4.y + lb4.y) * g4.y);                     \
    ob.z = f2bf((dd.z * rstd * lw4.z + lb4.z) * g4.z);                     \
    ob.w = f2bf((dd.w * rstd * lw4.w + lb4.w) * g4.w);                     \
    *(ushort4*)(z + off) = ob;                                             \
  }
  GNROW(acc0, 0)
  GNROW(acc1, 1)
  GNROW(acc2, 2)
  GNROW(acc3, 3)
#undef GNROW
}

// ---------------------------------------------------------------- launch ---
extern "C" void kernel_launch(void* const* d_in, const int* in_sizes, int n_in,
                              void* d_out, int out_size, void* d_ws, size_t ws_size,
                              hipStream_t stream) {
  const int B = 8, T = 1024, C = 768, H = 12, ph = 32, pw = 32;
  const int M = B * T;
  const int L = 64, NCH = T / L;

  const float* x        = (const float*)d_in[0];
  const float* W_r      = (const float*)d_in[1];
  const float* W_k      = (const float*)d_in[2];
  const float* W_v      = (const float*)d_in[3];
  const float* W_g      = (const float*)d_in[4];
  const float* W_o      = (const float*)d_in[5];
  const float* maa_x    = (const float*)d_in[6];
  const float* maa_w    = (const float*)d_in[7];
  const float* maa_k    = (const float*)d_in[8];
  const float* maa_v    = (const float*)d_in[9];
  const float* maa_r    = (const float*)d_in[10];
  const float* maa_g    = (const float*)d_in[11];
  const float* maa_w1   = (const float*)d_in[12];
  const float* maa_w2   = (const float*)d_in[13];
  const float* time_dec = (const float*)d_in[14];
  const float* dec_w1   = (const float*)d_in[15];
  const float* dec_w2   = (const float*)d_in[16];
  const float* faaaa    = (const float*)d_in[17];
  const float* ln_w     = (const float*)d_in[18];
  const float* ln_b     = (const float*)d_in[19];

  float* ws = (float*)d_ws;
  const size_t S = (size_t)M * C;
  float* F0 = ws + 0 * S;   // xx -> r -> kvb
  float* F1 = ws + 1 * S;   // xxx_bf -> k -> Scb
  float* F2 = ws + 2 * S;   // xw_bf -> w -> Kt (in place)
  float* F3 = ws + 3 * S;   // v
  float* F4 = ws + 4 * S;   // g
  float* F5 = ws + 5 * S;   // xr_bf | xk_bf -> Rt (fp32)
  float* F6 = ws + 6 * S;   // xv_bf | xg_bf -> z_bf
  float* t5    = ws + 7 * S;            // [M,160] fp32 -> bf16 W_r..W_g
  float* t6    = t5 + (size_t)M * 160;  // bf16 W_o + maa1T + decT
  float* aLb   = t6 + (size_t)M * 64;
  float* pdiag = aLb + (size_t)B * H * NCH * 64;
  float* dec_t = pdiag + (size_t)B * H * T;   // [M,64] t_bf scratch

  ushort* xxx_bf = (ushort*)F1;
  ushort* xw_bf = (ushort*)F2;
  ushort* xr_bf = (ushort*)F5;
  ushort* xk_bf = xr_bf + S;
  ushort* xv_bf = (ushort*)F6;
  ushort* xg_bf = xv_bf + S;
  ushort* z_bf  = (ushort*)F6;
  ushort* t_bf  = (ushort*)dec_t;       // [M,64] bf16
  float* kvb = F0;
  float* Scb = F1;
  const int WSZ = C * C;
  ushort* wr_bf = (ushort*)t5;
  ushort* wk_bf = wr_bf + WSZ;
  ushort* wv_bf = wk_bf + WSZ;
  ushort* wg_bf = wv_bf + WSZ;
  ushort* wo_bf = (ushort*)t6;
  ushort* maa1T = wo_bf + WSZ;          // [256,768]
  ushort* w1dT  = maa1T + 256 * 768;    // [128,768]
  ushort* w2dT  = w1dT + 128 * 768;     // [768,64]

  // 1. qshift (xx fp32, xxx bf16)
  {
    long total = (long)M * C;
    k_qshift<<<(int)((total + 255) / 256), 256, 0, stream>>>(
        x, maa_x, F0, xxx_bf, B, T, C, ph, pw);
  }
  // 2. maa_w1/dec transposes -> bf16; t5 = tanh(xxx @ maa_w1) via MFMA
  {
    dim3 gt(3, 256);
    k_w1t<<<gt, 256, 0, stream>>>(maa_w1, maa1T);
    k_decT<<<(128 * 768 + 768 * 64) / 256, 256, 0, stream>>>(
        dec_w1, dec_w2, w1dT, w2dT);
    dim3 grid(2, M / 128);
    k_gemm_bf<EPI_TANH, true, false><<<grid, 256, 0, stream>>>(
        xxx_bf, maa1T, nullptr, t5, M, 160, C);
  }
  // 3. mix5 (all outputs bf16)
  {
    dim3 grid(C / 64, M / 64);
    k_mix5f<<<grid, 256, 0, stream>>>(t5, maa_w2, x, F0, maa_w, maa_k, maa_v,
                                      maa_r, maa_g, xw_bf, xk_bf, xv_bf, xr_bf,
                                      xg_bf, C);
  }
  // 4. weight conversion (t5 data dead now)
  {
    dim3 grid((WSZ / 4 + 255) / 256, 5);
    k_cvt5<<<grid, 256, 0, stream>>>(W_r, W_k, W_v, W_g, W_o,
                                     wr_bf, wk_bf, wv_bf, wg_bf, wo_bf, WSZ);
  }
  // 5. big projections: ONE batched bf16 MFMA dispatch (grid.z = 4)
  {
    dim3 grid(C / 128, M / 128, 4);
    k_proj4<<<grid, 256, 0, stream>>>(xr_bf, xk_bf, xv_bf, xg_bf,
                                      wr_bf, wk_bf, wv_bf, wg_bf,
                                      F0, F1, F3, F4, M, C, C);
  }
  // 6. decay path on MFMA
  {
    dim3 g1(1, M / 128);
    k_gemm_bf<EPI_TANH, true, true><<<g1, 256, 0, stream>>>(
        xw_bf, w1dT, nullptr, t_bf, M, 64, C);
    dim3 g2(C / 128, M / 128);
    k_gemm_bf<EPI_BIAS, false, false><<<g2, 256, 0, stream>>>(
        t_bf, w2dT, time_dec, F2, M, C, 64);
  }
  // 7. chunked wkv6: pre -> kv -> scan -> intra(+GN+gate -> z bf16)
  k_wkv_pre<<<B * H * NCH, 64, 0, stream>>>(F0, F1, F2, faaaa, F5, F2,
                                            aLb, pdiag, B, T, C, H, L);
  k_wkv_kv<<<B * H * NCH, 256, 0, stream>>>(F2, F3, kvb, B, T, C, H, L);
  k_wkv_scan<<<B * H, 256, 0, stream>>>(kvb, aLb, Scb, NCH);
  k_wkv_intra<<<B * H * NCH, 256, 0, stream>>>(F5, F2, F3, pdiag, Scb, F4,
                                               ln_w, ln_b, z_bf, B, T, C, H, L);
  // 8. out = z @ W_o^T (bf16 MFMA)
  {
    dim3 grid(C / 128, M / 128);
    k_gemm_bf<EPI_NONE, false, false><<<grid, 256, 0, stream>>>(
        z_bf, wo_bf, nullptr, (float*)d_out, M, C, C);
  }
}

// Round 2
// 485.629 us; speedup vs baseline: 1.1066x; 1.0800x over previous
//
#include <hip/hip_runtime.h>
#include <math.h>

// ---------------------------------------------------------------------------
// TimeMix (RWKV-6 vision block) — round 11: k_wkv_intra 2-tile/32KB rewrite
// (GLDS staging, src-swizzled Rt, in-place P^T, pass-split phase 2) for
// occupancy 3->4-5 blocks/CU; parallel k_wkv_scan; LDS-reduce k_wkv_pre;
// GLDS k_wkv_kv. fp32 kept in the recurrence. B=8, T=1024, C=768, H=12.
// ---------------------------------------------------------------------------

#define EPI_NONE 0
#define EPI_TANH 1
#define EPI_RELU 2
#define EPI_BIAS 3

#define LPAD 68   // LDS row stride (floats) for 64-wide chunk tiles (mix5 etc)

typedef float f32x4 __attribute__((ext_vector_type(4)));
typedef __bf16 bf16x8 __attribute__((ext_vector_type(8)));

__device__ __forceinline__ ushort f2bf(float x) {
  unsigned u = __float_as_uint(x);
  return (ushort)((u + 0x7fffu + ((u >> 16) & 1u)) >> 16);
}

#define GLDS16(gp, lp)                                                   \
  __builtin_amdgcn_global_load_lds(                                      \
      (const __attribute__((address_space(1))) void*)(gp),               \
      (__attribute__((address_space(3))) void*)(lp), 16, 0, 0)

// ---------------------------------------------------------------- qshift ---
__global__ __launch_bounds__(256) void k_qshift(
    const float* __restrict__ x, const float* __restrict__ maa_x,
    float* __restrict__ xx, ushort* __restrict__ xxx_bf,
    int B, int T, int C, int ph, int pw) {
  long idx = (long)blockIdx.x * blockDim.x + threadIdx.x;
  long total = (long)B * T * C;
  if (idx >= total) return;
  int c = (int)(idx % C);
  long bt = idx / C;
  int t = (int)(bt % T);
  int quarter = (c & 63) >> 4;
  int hh = t / pw;
  int ww = t - hh * pw;
  long rowbase = (bt - t) * C;
  float sval = 0.f;
  int st = -1;
  if (quarter == 0)      { if (ww >= 1)      st = t - 1;  }
  else if (quarter == 1) { if (ww < pw - 1)  st = t + 1;  }
  else if (quarter == 2) { if (hh >= 1)      st = t - pw; }
  else                   { if (hh < ph - 1)  st = t + pw; }
  if (st >= 0) sval = x[rowbase + (long)st * C + c];
  float xval = x[idx];
  float d = sval - xval;
  xx[idx] = d;
  xxx_bf[idx] = f2bf(xval + d * maa_x[c]);
}

// ------------------------------------- maa_w1 transpose+convert to bf16 ----
__global__ __launch_bounds__(256) void k_w1t(
    const float* __restrict__ w1, ushort* __restrict__ out) {
  int n = blockIdx.y;
  int k = blockIdx.x * 256 + threadIdx.x;
  float v = (n < 160) ? w1[(size_t)k * 160 + n] : 0.f;
  out[(size_t)n * 768 + k] = f2bf(v);
}

// -------------------------- dec_w1 / dec_w2 transpose+convert to bf16 ------
__global__ __launch_bounds__(256) void k_decT(
    const float* __restrict__ w1, const float* __restrict__ w2,
    ushort* __restrict__ w1dT, ushort* __restrict__ w2dT) {
  int idx = blockIdx.x * 256 + threadIdx.x;
  if (idx < 128 * 768) {
    int n = idx / 768, k = idx - n * 768;
    float v = (n < 64) ? w1[(size_t)k * 64 + n] : 0.f;
    w1dT[idx] = f2bf(v);
  } else {
    int j = idx - 128 * 768;
    int n = j >> 6, k = j & 63;
    w2dT[j] = f2bf(w2[(size_t)k * 768 + n]);
  }
}

// ---------------------------------------------- mix5 fused GEMM+epilogue ---
__global__ __launch_bounds__(256) void k_mix5f(
    const float* __restrict__ t5, const float* __restrict__ maa_w2,
    const float* __restrict__ x, const float* __restrict__ xx,
    const float* __restrict__ maa_w, const float* __restrict__ maa_k,
    const float* __restrict__ maa_v, const float* __restrict__ maa_r,
    const float* __restrict__ maa_g,
    ushort* __restrict__ xw, ushort* __restrict__ xk, ushort* __restrict__ xvb,
    ushort* __restrict__ xr, ushort* __restrict__ xg, int C) {
  __shared__ float As[64][36];
  __shared__ float Bs[32][64];
  int tid = threadIdx.x;
  int m0 = blockIdx.y * 64, n0 = blockIdx.x * 64;
  int tx = tid & 15, ty = tid >> 4;
  int cb = n0 + tx * 4;
  float4 xv4[4], dd4[4];
#pragma unroll
  for (int i = 0; i < 4; i++) {
    size_t off = (size_t)(m0 + ty * 4 + i) * C + cb;
    xv4[i] = *(const float4*)(x + off);
    dd4[i] = *(const float4*)(xx + off);
  }

#pragma unroll
  for (int f = 0; f < 5; f++) {
    {
      int k4 = (tid & 7) * 4;
      int row = tid >> 3;
      const float* src = t5 + (size_t)(m0 + row) * 160 + f * 32 + k4;
      float4 v0 = *(const float4*)src;
      float4 v1 = *(const float4*)(src + 32 * 160);
      *(float4*)(&As[row][k4]) = v0;
      *(float4*)(&As[row + 32][k4]) = v1;
    }
    {
      int col = (tid & 15) * 4, kk = tid >> 4;
      const float* src = maa_w2 + (size_t)(f * 32 + kk) * C + n0 + col;
      *(float4*)(&Bs[kk][col]) = *(const float4*)src;
      *(float4*)(&Bs[kk + 16][col]) = *(const float4*)(src + (size_t)16 * C);
    }
    __syncthreads();
    float acc[4][4];
#pragma unroll
    for (int i = 0; i < 4; i++)
#pragma unroll
      for (int j = 0; j < 4; j++) acc[i][j] = 0.f;
#pragma unroll
    for (int kk = 0; kk < 32; kk++) {
      float4 b4 = *(const float4*)(&Bs[kk][tx * 4]);
#pragma unroll
      for (int i = 0; i < 4; i++) {
        float a = As[ty * 4 + i][kk];
        acc[i][0] = fmaf(a, b4.x, acc[i][0]);
        acc[i][1] = fmaf(a, b4.y, acc[i][1]);
        acc[i][2] = fmaf(a, b4.z, acc[i][2]);
        acc[i][3] = fmaf(a, b4.w, acc[i][3]);
      }
    }
    __syncthreads();
    const float* maa_f = (f == 0) ? maa_w : (f == 1) ? maa_k
                        : (f == 2) ? maa_v : (f == 3) ? maa_r : maa_g;
    ushort* dst = (f == 0) ? xw : (f == 1) ? xk
                 : (f == 2) ? xvb : (f == 3) ? xr : xg;
    float4 mf = *(const float4*)(maa_f + cb);
#pragma unroll
    for (int i = 0; i < 4; i++) {
      size_t off = (size_t)(m0 + ty * 4 + i) * C + cb;
      ushort4 ob;
      ob.x = f2bf(xv4[i].x + dd4[i].x * (mf.x + acc[i][0]));
      ob.y = f2bf(xv4[i].y + dd4[i].y * (mf.y + acc[i][1]));
      ob.z = f2bf(xv4[i].z + dd4[i].z * (mf.z + acc[i][2]));
      ob.w = f2bf(xv4[i].w + dd4[i].w * (mf.w + acc[i][3]));
      *(ushort4*)(dst + off) = ob;
    }
  }
}

// -------------------------------------------- fp32 -> bf16 cvt (5 arrays) --
__global__ __launch_bounds__(256) void k_cvt5(
    const float* __restrict__ s0, const float* __restrict__ s1,
    const float* __restrict__ s2, const float* __restrict__ s3,
    const float* __restrict__ s4,
    ushort* __restrict__ d0, ushort* __restrict__ d1,
    ushort* __restrict__ d2, ushort* __restrict__ d3,
    ushort* __restrict__ d4, int n) {
  const float* s;
  ushort* d;
  switch (blockIdx.y) {
    case 0: s = s0; d = d0; break;
    case 1: s = s1; d = d1; break;
    case 2: s = s2; d = d2; break;
    case 3: s = s3; d = d3; break;
    default: s = s4; d = d4; break;
  }
  int i = (blockIdx.x * 256 + threadIdx.x) * 4;
  if (i >= n) return;
  float4 v = *(const float4*)(s + i);
  ushort4 o;
  o.x = f2bf(v.x); o.y = f2bf(v.y); o.z = f2bf(v.z); o.w = f2bf(v.w);
  *(ushort4*)(d + i) = o;
}

// ----------------------------------------------------- bf16 MFMA GEMM ------
template <int EPI, bool NMASK, bool OBF16>
__global__ __launch_bounds__(256) void k_gemm_bf(
    const ushort* __restrict__ A, const ushort* __restrict__ W,
    const float* __restrict__ bias, void* __restrict__ Cm,
    int M, int N, int K) {
  __shared__ ushort Al[128 * 32];
  __shared__ ushort Bl[128 * 32];
  int tid = threadIdx.x;
  int m0 = blockIdx.y * 128, n0 = blockIdx.x * 128;
  int lane = tid & 63, wave = tid >> 6;
  int wm = (wave >> 1) * 64, wn = (wave & 1) * 64;
  int lm = lane & 15, lk = (lane >> 4) * 8;
  f32x4 acc[4][4];
#pragma unroll
  for (int i = 0; i < 4; i++)
#pragma unroll
    for (int j = 0; j < 4; j++) acc[i][j] = (f32x4){0.f, 0.f, 0.f, 0.f};

  int arow = tid >> 2, achunk = (tid & 3) * 8;
  const ushort* Ag = A + (size_t)(m0 + arow) * K + achunk;
  const ushort* Wg = W + (size_t)(n0 + arow) * K + achunk;
  ushort* Ald = Al + tid * 8;
  ushort* Bld = Bl + tid * 8;

  for (int k0 = 0; k0 < K; k0 += 32) {
    GLDS16(Ag + k0, Ald);
    GLDS16(Ag + (size_t)64 * K + k0, Ald + 2048);
    GLDS16(Wg + k0, Bld);
    GLDS16(Wg + (size_t)64 * K + k0, Bld + 2048);
    __syncthreads();
    bf16x8 af[4], bf[4];
#pragma unroll
    for (int i = 0; i < 4; i++)
      af[i] = *(const bf16x8*)&Al[(wm + i * 16 + lm) * 32 + lk];
#pragma unroll
    for (int j = 0; j < 4; j++)
      bf[j] = *(const bf16x8*)&Bl[(wn + j * 16 + lm) * 32 + lk];
#pragma unroll
    for (int i = 0; i < 4; i++)
#pragma unroll
      for (int j = 0; j < 4; j++)
        acc[i][j] = __builtin_amdgcn_mfma_f32_16x16x32_bf16(
            af[i], bf[j], acc[i][j], 0, 0, 0);
    __syncthreads();
  }
  int rq = (lane >> 4) * 4;
#pragma unroll
  for (int i = 0; i < 4; i++) {
#pragma unroll
    for (int j = 0; j < 4; j++) {
      int gn = n0 + wn + j * 16 + lm;
      if (NMASK && gn >= N) continue;
      float bv = (EPI == EPI_BIAS) ? bias[gn] : 0.f;
#pragma unroll
      for (int q = 0; q < 4; q++) {
        int gm = m0 + wm + i * 16 + rq + q;
        float val = acc[i][j][q];
        if (EPI == EPI_BIAS) val += bv;
        if (EPI == EPI_RELU) val = fmaxf(val, 0.f);
        if (EPI == EPI_TANH) val = tanhf(val);
        if (OBF16) ((ushort*)Cm)[(size_t)gm * N + gn] = f2bf(val);
        else       ((float*)Cm)[(size_t)gm * N + gn] = val;
      }
    }
  }
}

// --------------------------------- batched 4-projection bf16 MFMA GEMM -----
__global__ __launch_bounds__(256) void k_proj4(
    const ushort* __restrict__ A0, const ushort* __restrict__ A1,
    const ushort* __restrict__ A2, const ushort* __restrict__ A3,
    const ushort* __restrict__ W0, const ushort* __restrict__ W1,
    const ushort* __restrict__ W2, const ushort* __restrict__ W3,
    float* __restrict__ C0, float* __restrict__ C1,
    float* __restrict__ C2, float* __restrict__ C3,
    int M, int N, int K) {
  int z = blockIdx.z;
  const ushort* A = (z == 0) ? A0 : (z == 1) ? A1 : (z == 2) ? A2 : A3;
  const ushort* W = (z == 0) ? W0 : (z == 1) ? W1 : (z == 2) ? W2 : W3;
  float* Cm       = (z == 0) ? C0 : (z == 1) ? C1 : (z == 2) ? C2 : C3;
  __shared__ ushort Al[128 * 32];
  __shared__ ushort Bl[128 * 32];
  int tid = threadIdx.x;
  int m0 = blockIdx.y * 128, n0 = blockIdx.x * 128;
  int lane = tid & 63, wave = tid >> 6;
  int wm = (wave >> 1) * 64, wn = (wave & 1) * 64;
  int lm = lane & 15, lk = (lane >> 4) * 8;
  f32x4 acc[4][4];
#pragma unroll
  for (int i = 0; i < 4; i++)
#pragma unroll
    for (int j = 0; j < 4; j++) acc[i][j] = (f32x4){0.f, 0.f, 0.f, 0.f};

  int arow = tid >> 2, achunk = (tid & 3) * 8;
  const ushort* Ag = A + (size_t)(m0 + arow) * K + achunk;
  const ushort* Wg = W + (size_t)(n0 + arow) * K + achunk;
  ushort* Ald = Al + tid * 8;
  ushort* Bld = Bl + tid * 8;

  for (int k0 = 0; k0 < K; k0 += 32) {
    GLDS16(Ag + k0, Ald);
    GLDS16(Ag + (size_t)64 * K + k0, Ald + 2048);
    GLDS16(Wg + k0, Bld);
    GLDS16(Wg + (size_t)64 * K + k0, Bld + 2048);
    __syncthreads();
    bf16x8 af[4], bf[4];
#pragma unroll
    for (int i = 0; i < 4; i++)
      af[i] = *(const bf16x8*)&Al[(wm + i * 16 + lm) * 32 + lk];
#pragma unroll
    for (int j = 0; j < 4; j++)
      bf[j] = *(const bf16x8*)&Bl[(wn + j * 16 + lm) * 32 + lk];
#pragma unroll
    for (int i = 0; i < 4; i++)
#pragma unroll
      for (int j = 0; j < 4; j++)
        acc[i][j] = __builtin_amdgcn_mfma_f32_16x16x32_bf16(
            af[i], bf[j], acc[i][j], 0, 0, 0);
    __syncthreads();
  }
  bool relu = (z == 3);
  int rq = (lane >> 4) * 4;
#pragma unroll
  for (int i = 0; i < 4; i++) {
#pragma unroll
    for (int j = 0; j < 4; j++) {
      int gn = n0 + wn + j * 16 + lm;
#pragma unroll
      for (int q = 0; q < 4; q++) {
        int gm = m0 + wm + i * 16 + rq + q;
        float val = acc[i][j][q];
        if (relu) val = fmaxf(val, 0.f);
        Cm[(size_t)gm * N + gn] = val;
      }
    }
  }
}

// ------------------------------------------------- chunked WKV: phase pre --
// pdiag via LDS stage + per-row sum (replaces 64x serial 6-deep shfl chains).
__global__ __launch_bounds__(64) void k_wkv_pre(
    const float* __restrict__ r, const float* __restrict__ k,
    const float* __restrict__ w, const float* __restrict__ u,
    float* __restrict__ rt, float* __restrict__ kt,
    float* __restrict__ aL, float* __restrict__ pdiag,
    int B, int T, int C, int H, int L) {
  __shared__ float pls[64 * 65];
  int nch = T / L;
  int blk = blockIdx.x;
  int bh = blk / nch, c = blk - bh * nch;
  int b = bh / H, h = bh - b * H;
  int j = threadIdx.x;
  float uj = u[h * 64 + j];
  float cum = 0.f;
  long base = ((long)b * T + (long)c * L) * C + h * 64 + j;
  for (int tau = 0; tau < L; tau++) {
    long off = base + (long)tau * C;
    float wv = w[off];
    float rv = r[off];
    float kv = k[off];
    float e = expf(wv);
    rt[off] = rv * expf(-cum);
    cum += e;
    kt[off] = kv * expf(cum);
    pls[tau * 65 + j] = rv * uj * kv;
  }
  aL[((long)bh * nch + c) * 64 + j] = expf(-cum);
  __syncthreads();
  float s0 = 0.f, s1 = 0.f, s2 = 0.f, s3 = 0.f;
#pragma unroll
  for (int q = 0; q < 16; q++) {
    float4 p4 = *(const float4*)(pls + j * 65 + q * 4);
    s0 += p4.x; s1 += p4.y; s2 += p4.z; s3 += p4.w;
  }
  pdiag[(long)bh * T + c * L + j] = (s0 + s1) + (s2 + s3);
}

// --------------------------------------- chunked WKV: per-chunk KV outer ---
// GLDS staging (no VGPR roundtrip), unpadded 16KB tiles.
__global__ __launch_bounds__(256) void k_wkv_kv(
    const float* __restrict__ kt, const float* __restrict__ v,
    float* __restrict__ kvb, int B, int T, int C, int H, int L) {
  int nch = T / L;
  int blk = blockIdx.x;
  int bh = blk / nch, c = blk - bh * nch;
  int b = bh / H, h = bh - b * H;
  __shared__ float Ks[64 * 64];
  __shared__ float Vs[64 * 64];
  int tid = threadIdx.x;
  int lane = tid & 63, jg = tid >> 6;
  long cbase = ((long)b * T + (long)c * L) * C + h * 64;
#pragma unroll
  for (int i = 0; i < 4; i++) {
    int chunk = jg * 4 + i;
    int row = chunk * 4 + (lane >> 4);
    int cq = lane & 15;
    GLDS16(kt + cbase + (long)row * C + cq * 4, Ks + chunk * 256);
    GLDS16(v + cbase + (long)row * C + cq * 4, Vs + chunk * 256);
  }
  __syncthreads();
  float acc[16];
#pragma unroll
  for (int q = 0; q < 16; q++) acc[q] = 0.f;
  for (int s = 0; s < 64; s++) {
    float vi = Vs[s * 64 + lane];
#pragma unroll
    for (int q4 = 0; q4 < 4; q4++) {
      float4 kk = *(const float4*)(Ks + s * 64 + jg * 16 + q4 * 4);
      acc[q4 * 4 + 0] = fmaf(kk.x, vi, acc[q4 * 4 + 0]);
      acc[q4 * 4 + 1] = fmaf(kk.y, vi, acc[q4 * 4 + 1]);
      acc[q4 * 4 + 2] = fmaf(kk.z, vi, acc[q4 * 4 + 2]);
      acc[q4 * 4 + 3] = fmaf(kk.w, vi, acc[q4 * 4 + 3]);
    }
  }
  float* out = kvb + ((long)bh * nch + c) * 4096;
#pragma unroll
  for (int q = 0; q < 16; q++) out[(jg * 16 + q) * 64 + lane] = acc[q];
}

// ---------------------------------------- chunked WKV: state prefix scan ---
// Elementwise-independent across the 4096 state entries -> 16x more blocks.
__global__ __launch_bounds__(256) void k_wkv_scan(
    const float* __restrict__ kvb, const float* __restrict__ aL,
    float* __restrict__ Scb, int nch) {
  int bh = blockIdx.x >> 4;
  int e = ((blockIdx.x & 15) << 8) + threadIdx.x;   // 0..4095
  float S = 0.f;
  for (int c = 0; c < nch; c++) {
    long cb = ((long)bh * nch + c) * 4096 + e;
    Scb[cb] = S;
    S = aL[((long)bh * nch + c) * 64 + (e >> 6)] * (S + kvb[cb]);
  }
}

// ------------- chunked WKV: intra + inter + groupnorm*gate (fused) ---------
// Two unpadded 16KB tiles (32KB total -> 4-5 blocks/CU):
//   TA: Rt(src-swizzled) -> V -> Rt^T     TB: Kt -> P^T (in place, wave-own)
// All staging via global_load_lds; rreg read applies the same XOR swizzle
// the GLDS source applied (LDS stays linear, per m173). Rt^T write uses a
// wave-uniform static switch so every rreg index is compile-time (rule #20).
__global__ __launch_bounds__(256, 4) void k_wkv_intra(
    const float* __restrict__ rt, const float* __restrict__ kt,
    const float* __restrict__ v, const float* __restrict__ pdiag,
    const float* __restrict__ Scb, const float* __restrict__ g,
    const float* __restrict__ ln_w, const float* __restrict__ ln_b,
    ushort* __restrict__ z, int B, int T, int C, int H, int L) {
  int nch = T / L;
  int blk = blockIdx.x;
  int bh = blk / nch, c = blk - bh * nch;
  int b = bh / H, h = bh - b * H;
  __shared__ float TA[64 * 64];
  __shared__ float TB[64 * 64];
  int tid = threadIdx.x;
  int lane = tid & 63, wid = tid >> 6;
  int tau = lane;
  long cbase = ((long)b * T + (long)c * L) * C + h * 64;
  const float* scp = Scb + ((long)bh * nch + c) * 4096;

  // --- stage: Rt (swizzled source) -> TA, Kt -> TB ---
#pragma unroll
  for (int i = 0; i < 4; i++) {
    int chunk = wid * 4 + i;
    int row = chunk * 4 + (lane >> 4);
    int cq = lane & 15;
    GLDS16(rt + cbase + (long)row * C + ((cq ^ (row & 15)) * 4),
           TA + chunk * 256);
    GLDS16(kt + cbase + (long)row * C + cq * 4, TB + chunk * 256);
  }
  __syncthreads();   // Rt+Kt resident (barrier drains vmcnt)

  // --- rreg: full Rt row per lane, via the inverse swizzle (4-way, cheap) --
  float4 rreg[16];
#pragma unroll
  for (int q = 0; q < 16; q++)
    rreg[q] = *(const float4*)(TA + tau * 64 + ((q ^ (tau & 15)) * 4));
  float pd = pdiag[(long)bh * T + c * L + tau];
  __syncthreads();   // all rreg reads done; TA reusable

  // --- stage V -> TA (lands during phase 1) ---
#pragma unroll
  for (int i = 0; i < 4; i++) {
    int chunk = wid * 4 + i;
    int row = chunk * 4 + (lane >> 4);
    GLDS16(v + cbase + (long)row * C + (lane & 15) * 4, TA + chunk * 256);
  }

  // --- phase 1: P^T row s over Kt row s (wave-own rows 16*wid..16*wid+15) --
#pragma unroll 2
  for (int ss = 0; ss < 16; ss++) {
    int s = wid * 16 + ss;
    float a0 = 0.f, a1 = 0.f, a2 = 0.f, a3 = 0.f;
#pragma unroll
    for (int q = 0; q < 16; q++) {
      float4 kk = *(const float4*)(TB + s * 64 + q * 4);   // broadcast
      a0 = fmaf(rreg[q].x, kk.x, a0);
      a1 = fmaf(rreg[q].y, kk.y, a1);
      a2 = fmaf(rreg[q].z, kk.z, a2);
      a3 = fmaf(rreg[q].w, kk.w, a3);
    }
    float a = (a0 + a1) + (a2 + a3);
    float val = (s < tau) ? a : (s == tau ? pd : 0.f);
    TB[s * 64 + tau] = val;
  }
  __syncthreads();   // P^T complete everywhere; V resident

  // --- pass A: acc += P^T ⊗ V ---
  int row0 = wid * 16 + ((lane >> 4) << 2);   // 4 consecutive output rows
  int c0 = (lane & 15) * 4;                   // 4 consecutive channels
  float4 acc0 = {0.f, 0.f, 0.f, 0.f};
  float4 acc1 = {0.f, 0.f, 0.f, 0.f};
  float4 acc2 = {0.f, 0.f, 0.f, 0.f};
  float4 acc3 = {0.f, 0.f, 0.f, 0.f};
#define FMA1(A, P, V4)                 \
  A.x = fmaf(P, V4.x, A.x);            \
  A.y = fmaf(P, V4.y, A.y);            \
  A.z = fmaf(P, V4.z, A.z);            \
  A.w = fmaf(P, V4.w, A.w);
#pragma unroll 4
  for (int j = 0; j < 64; j++) {
    float4 pp = *(const float4*)(TB + j * 64 + row0);   // 16-lane multicast
    float4 vv = *(const float4*)(TA + j * 64 + c0);     // 2-way (free)
    FMA1(acc0, pp.x, vv);
    FMA1(acc1, pp.y, vv);
    FMA1(acc2, pp.z, vv);
    FMA1(acc3, pp.w, vv);
  }
  __syncthreads();   // V reads done; TA reusable

  // --- Rt^T -> TA (wave wid owns q-rows [16*wid, 16*wid+16)) ---
#define WRQ(SG)                                                          \
  {                                                                      \
    _Pragma("unroll") for (int qq = 0; qq < 16; qq++) {                  \
      const float* rp = (const float*)&rreg[(SG) * 4 + (qq >> 2)];       \
      TA[((SG) * 16 + qq) * 64 + tau] = rp[qq & 3];                      \
    }                                                                    \
  }
  if (wid == 0)      WRQ(0)
  else if (wid == 1) WRQ(1)
  else if (wid == 2) WRQ(2)
  else               WRQ(3)
#undef WRQ
  __syncthreads();

  // --- pass B: acc += Rt^T ⊗ S_prev (S from global, coalesced, L1 x4) ---
#pragma unroll 4
  for (int j = 0; j < 64; j++) {
    float4 rr = *(const float4*)(TA + j * 64 + row0);   // 16-lane multicast
    float4 ssv = *(const float4*)(scp + j * 64 + c0);
    FMA1(acc0, rr.x, ssv);
    FMA1(acc1, rr.y, ssv);
    FMA1(acc2, rr.z, ssv);
    FMA1(acc3, rr.w, ssv);
  }
#undef FMA1

  // ---- fused groupnorm (per row over this head's 64 channels) * gate ----
  float4 lw4 = *(const float4*)(ln_w + h * 64 + c0);
  float4 lb4 = *(const float4*)(ln_b + h * 64 + c0);
#define GNROW(A, m)                                                        \
  {                                                                        \
    float s1 = (A.x + A.y) + (A.z + A.w);                                  \
    s1 += __shfl_xor(s1, 1, 64);                                           \
    s1 += __shfl_xor(s1, 2, 64);                                           \
    s1 += __shfl_xor(s1, 4, 64);                                           \
    s1 += __shfl_xor(s1, 8, 64);                                           \
    float mu = s1 * (1.f / 64.f);                                          \
    float4 dd;                                                             \
    dd.x = A.x - mu; dd.y = A.y - mu; dd.z = A.z - mu; dd.w = A.w - mu;    \
    float s2 = (dd.x * dd.x + dd.y * dd.y) + (dd.z * dd.z + dd.w * dd.w);  \
    s2 += __shfl_xor(s2, 1, 64);                                           \
    s2 += __shfl_xor(s2, 2, 64);                                           \
    s2 += __shfl_xor(s2, 4, 64);                                           \
    s2 += __shfl_xor(s2, 8, 64);                                           \
    float rstd = rsqrtf(s2 * (1.f / 64.f) + 1e-5f);                        \
    long off = cbase + (long)(row0 + m) * C + c0;                          \
    float4 g4 = *(const float4*)(g + off);                                 \
    ushort4 ob;                                                            \
    ob.x = f2bf((dd.x * rstd * lw4.x + lb4.x) * g4.x);                     \
    ob.y = f2bf((dd.y * rstd * lw4.y + lb4.y) * g4.y);                     \
    ob.z = f2bf((dd.z * rstd * lw4.z + lb4.z) * g4.z);                     \
    ob.w = f2bf((dd.w * rstd * lw4.w + lb4.w) * g4.w);                     \
    *(ushort4*)(z + off) = ob;                                             \
  }
  GNROW(acc0, 0)
  GNROW(acc1, 1)
  GNROW(acc2, 2)
  GNROW(acc3, 3)
#undef GNROW
}

// ---------------------------------------------------------------- launch ---
extern "C" void kernel_launch(void* const* d_in, const int* in_sizes, int n_in,
                              void* d_out, int out_size, void* d_ws, size_t ws_size,
                              hipStream_t stream) {
  const int B = 8, T = 1024, C = 768, H = 12, ph = 32, pw = 32;
  const int M = B * T;
  const int L = 64, NCH = T / L;

  const float* x        = (const float*)d_in[0];
  const float* W_r      = (const float*)d_in[1];
  const float* W_k      = (const float*)d_in[2];
  const float* W_v      = (const float*)d_in[3];
  const float* W_g      = (const float*)d_in[4];
  const float* W_o      = (const float*)d_in[5];
  const float* maa_x    = (const float*)d_in[6];
  const float* maa_w    = (const float*)d_in[7];
  const float* maa_k    = (const float*)d_in[8];
  const float* maa_v    = (const float*)d_in[9];
  const float* maa_r    = (const float*)d_in[10];
  const float* maa_g    = (const float*)d_in[11];
  const float* maa_w1   = (const float*)d_in[12];
  const float* maa_w2   = (const float*)d_in[13];
  const float* time_dec = (const float*)d_in[14];
  const float* dec_w1   = (const float*)d_in[15];
  const float* dec_w2   = (const float*)d_in[16];
  const float* faaaa    = (const float*)d_in[17];
  const float* ln_w     = (const float*)d_in[18];
  const float* ln_b     = (const float*)d_in[19];

  float* ws = (float*)d_ws;
  const size_t S = (size_t)M * C;
  float* F0 = ws + 0 * S;   // xx -> r -> kvb
  float* F1 = ws + 1 * S;   // xxx_bf -> k -> Scb
  float* F2 = ws + 2 * S;   // xw_bf -> w -> Kt (in place)
  float* F3 = ws + 3 * S;   // v
  float* F4 = ws + 4 * S;   // g
  float* F5 = ws + 5 * S;   // xr_bf | xk_bf -> Rt (fp32)
  float* F6 = ws + 6 * S;   // xv_bf | xg_bf -> z_bf
  float* t5    = ws + 7 * S;            // [M,160] fp32 -> bf16 W_r..W_g
  float* t6    = t5 + (size_t)M * 160;  // bf16 W_o + maa1T + decT
  float* aLb   = t6 + (size_t)M * 64;
  float* pdiag = aLb + (size_t)B * H * NCH * 64;
  float* dec_t = pdiag + (size_t)B * H * T;   // [M,64] t_bf scratch

  ushort* xxx_bf = (ushort*)F1;
  ushort* xw_bf = (ushort*)F2;
  ushort* xr_bf = (ushort*)F5;
  ushort* xk_bf = xr_bf + S;
  ushort* xv_bf = (ushort*)F6;
  ushort* xg_bf = xv_bf + S;
  ushort* z_bf  = (ushort*)F6;
  ushort* t_bf  = (ushort*)dec_t;       // [M,64] bf16
  float* kvb = F0;
  float* Scb = F1;
  const int WSZ = C * C;
  ushort* wr_bf = (ushort*)t5;
  ushort* wk_bf = wr_bf + WSZ;
  ushort* wv_bf = wk_bf + WSZ;
  ushort* wg_bf = wv_bf + WSZ;
  ushort* wo_bf = (ushort*)t6;
  ushort* maa1T = wo_bf + WSZ;          // [256,768]
  ushort* w1dT  = maa1T + 256 * 768;    // [128,768]
  ushort* w2dT  = w1dT + 128 * 768;     // [768,64]

  // 1. qshift (xx fp32, xxx bf16)
  {
    long total = (long)M * C;
    k_qshift<<<(int)((total + 255) / 256), 256, 0, stream>>>(
        x, maa_x, F0, xxx_bf, B, T, C, ph, pw);
  }
  // 2. maa_w1/dec transposes -> bf16; t5 = tanh(xxx @ maa_w1) via MFMA
  {
    dim3 gt(3, 256);
    k_w1t<<<gt, 256, 0, stream>>>(maa_w1, maa1T);
    k_decT<<<(128 * 768 + 768 * 64) / 256, 256, 0, stream>>>(
        dec_w1, dec_w2, w1dT, w2dT);
    dim3 grid(2, M / 128);
    k_gemm_bf<EPI_TANH, true, false><<<grid, 256, 0, stream>>>(
        xxx_bf, maa1T, nullptr, t5, M, 160, C);
  }
  // 3. mix5 (all outputs bf16)
  {
    dim3 grid(C / 64, M / 64);
    k_mix5f<<<grid, 256, 0, stream>>>(t5, maa_w2, x, F0, maa_w, maa_k, maa_v,
                                      maa_r, maa_g, xw_bf, xk_bf, xv_bf, xr_bf,
                                      xg_bf, C);
  }
  // 4. weight conversion (t5 data dead now)
  {
    dim3 grid((WSZ / 4 + 255) / 256, 5);
    k_cvt5<<<grid, 256, 0, stream>>>(W_r, W_k, W_v, W_g, W_o,
                                     wr_bf, wk_bf, wv_bf, wg_bf, wo_bf, WSZ);
  }
  // 5. big projections: ONE batched bf16 MFMA dispatch (grid.z = 4)
  {
    dim3 grid(C / 128, M / 128, 4);
    k_proj4<<<grid, 256, 0, stream>>>(xr_bf, xk_bf, xv_bf, xg_bf,
                                      wr_bf, wk_bf, wv_bf, wg_bf,
                                      F0, F1, F3, F4, M, C, C);
  }
  // 6. decay path on MFMA
  {
    dim3 g1(1, M / 128);
    k_gemm_bf<EPI_TANH, true, true><<<g1, 256, 0, stream>>>(
        xw_bf, w1dT, nullptr, t_bf, M, 64, C);
    dim3 g2(C / 128, M / 128);
    k_gemm_bf<EPI_BIAS, false, false><<<g2, 256, 0, stream>>>(
        t_bf, w2dT, time_dec, F2, M, C, 64);
  }
  // 7. chunked wkv6: pre -> kv -> scan -> intra(+GN+gate -> z bf16)
  k_wkv_pre<<<B * H * NCH, 64, 0, stream>>>(F0, F1, F2, faaaa, F5, F2,
                                            aLb, pdiag, B, T, C, H, L);
  k_wkv_kv<<<B * H * NCH, 256, 0, stream>>>(F2, F3, kvb, B, T, C, H, L);
  k_wkv_scan<<<B * H * 16, 256, 0, stream>>>(kvb, aLb, Scb, NCH);
  k_wkv_intra<<<B * H * NCH, 256, 0, stream>>>(F5, F2, F3, pdiag, Scb, F4,
                                               ln_w, ln_b, z_bf, B, T, C, H, L);
  // 8. out = z @ W_o^T (bf16 MFMA)
  {
    dim3 grid(C / 128, M / 128);
    k_gemm_bf<EPI_NONE, false, false><<<grid, 256, 0, stream>>>(
        z_bf, wo_bf, nullptr, (float*)d_out, M, C, C);
  }
}

// Round 3
// 447.675 us; speedup vs baseline: 1.2004x; 1.0848x over previous
//
#include <hip/hip_runtime.h>
#include <math.h>

// ---------------------------------------------------------------------------
// TimeMix (RWKV-6 vision block) — round 12: k_mix5f (VALU, 10-barrier,
// latency-bound, 78us) replaced by k_mix5m: MFMA 16x16x32 per f, operands
// straight from global (bf16 t5 + pre-transposed bf16 maa_w2, L2-resident),
// zero LDS, zero barriers, x/xx hoisted. t5 GEMM now emits bf16 directly.
// B=8, T=1024, C=768, H=12.
// ---------------------------------------------------------------------------

#define EPI_NONE 0
#define EPI_TANH 1
#define EPI_RELU 2
#define EPI_BIAS 3

typedef float f32x4 __attribute__((ext_vector_type(4)));
typedef __bf16 bf16x8 __attribute__((ext_vector_type(8)));

__device__ __forceinline__ ushort f2bf(float x) {
  unsigned u = __float_as_uint(x);
  return (ushort)((u + 0x7fffu + ((u >> 16) & 1u)) >> 16);
}

#define GLDS16(gp, lp)                                                   \
  __builtin_amdgcn_global_load_lds(                                      \
      (const __attribute__((address_space(1))) void*)(gp),               \
      (__attribute__((address_space(3))) void*)(lp), 16, 0, 0)

// ---------------------------------------------------------------- qshift ---
__global__ __launch_bounds__(256) void k_qshift(
    const float* __restrict__ x, const float* __restrict__ maa_x,
    float* __restrict__ xx, ushort* __restrict__ xxx_bf,
    int B, int T, int C, int ph, int pw) {
  long idx = (long)blockIdx.x * blockDim.x + threadIdx.x;
  long total = (long)B * T * C;
  if (idx >= total) return;
  int c = (int)(idx % C);
  long bt = idx / C;
  int t = (int)(bt % T);
  int quarter = (c & 63) >> 4;
  int hh = t / pw;
  int ww = t - hh * pw;
  long rowbase = (bt - t) * C;
  float sval = 0.f;
  int st = -1;
  if (quarter == 0)      { if (ww >= 1)      st = t - 1;  }
  else if (quarter == 1) { if (ww < pw - 1)  st = t + 1;  }
  else if (quarter == 2) { if (hh >= 1)      st = t - pw; }
  else                   { if (hh < ph - 1)  st = t + pw; }
  if (st >= 0) sval = x[rowbase + (long)st * C + c];
  float xval = x[idx];
  float d = sval - xval;
  xx[idx] = d;
  xxx_bf[idx] = f2bf(xval + d * maa_x[c]);
}

// ------------------------------------- maa_w1 transpose+convert to bf16 ----
__global__ __launch_bounds__(256) void k_w1t(
    const float* __restrict__ w1, ushort* __restrict__ out) {
  int n = blockIdx.y;
  int k = blockIdx.x * 256 + threadIdx.x;
  float v = (n < 160) ? w1[(size_t)k * 160 + n] : 0.f;
  out[(size_t)n * 768 + k] = f2bf(v);
}

// ------------------------- maa_w2 transpose+convert to bf16 [768][160] -----
__global__ __launch_bounds__(256) void k_w2t(
    const float* __restrict__ w2, ushort* __restrict__ w2T) {
  int idx = blockIdx.x * 256 + threadIdx.x;   // 0 .. 768*160-1
  int c = idx / 160, kk = idx - c * 160;
  w2T[idx] = f2bf(w2[(size_t)kk * 768 + c]);
}

// -------------------------- dec_w1 / dec_w2 transpose+convert to bf16 ------
__global__ __launch_bounds__(256) void k_decT(
    const float* __restrict__ w1, const float* __restrict__ w2,
    ushort* __restrict__ w1dT, ushort* __restrict__ w2dT) {
  int idx = blockIdx.x * 256 + threadIdx.x;
  if (idx < 128 * 768) {
    int n = idx / 768, k = idx - n * 768;
    float v = (n < 64) ? w1[(size_t)k * 64 + n] : 0.f;
    w1dT[idx] = f2bf(v);
  } else {
    int j = idx - 128 * 768;
    int n = j >> 6, k = j & 63;
    w2dT[j] = f2bf(w2[(size_t)k * 768 + n]);
  }
}

// --------------------------- mix5 on MFMA, no LDS, no barriers -------------
// out_f = x + xx*(maa_f + t5[:,f*32:(f+1)*32] @ maa_w2[f])  (5 outputs, bf16)
// A-frags from bf16 t5 [M,160]; B-frags from bf16 w2T [768,160] (L2-res).
// Tile: 64 rows x 128 cols; wave w owns rows [16w,16w+16), 8 col-frags.
__global__ __launch_bounds__(256) void k_mix5m(
    const ushort* __restrict__ t5b, const ushort* __restrict__ w2T,
    const float* __restrict__ x, const float* __restrict__ xx,
    const float* __restrict__ maa_w, const float* __restrict__ maa_k,
    const float* __restrict__ maa_v, const float* __restrict__ maa_r,
    const float* __restrict__ maa_g,
    ushort* __restrict__ xw, ushort* __restrict__ xk, ushort* __restrict__ xvb,
    ushort* __restrict__ xr, ushort* __restrict__ xg, int C) {
  int tid = threadIdx.x;
  int lane = tid & 63, wid = tid >> 6;
  int m0 = blockIdx.y * 64, n0 = blockIdx.x * 128;
  int lm = lane & 15, lk = (lane >> 4) * 8;
  int rq = (lane >> 4) * 4;
  const ushort* ap = t5b + (size_t)(m0 + wid * 16 + lm) * 160 + lk;

  // hoist x/xx (each element read once, not 5x)
  float xh[8][4], dh[8][4];
#pragma unroll
  for (int j = 0; j < 8; j++)
#pragma unroll
    for (int q = 0; q < 4; q++) {
      size_t off = (size_t)(m0 + wid * 16 + rq + q) * C + (n0 + j * 16 + lm);
      xh[j][q] = x[off];
      dh[j][q] = xx[off];
    }

#pragma unroll
  for (int f = 0; f < 5; f++) {
    bf16x8 af = *(const bf16x8*)(ap + f * 32);
    f32x4 acc[8];
#pragma unroll
    for (int j = 0; j < 8; j++) {
      bf16x8 bfj = *(const bf16x8*)(w2T +
          (size_t)(n0 + j * 16 + lm) * 160 + f * 32 + lk);
      acc[j] = __builtin_amdgcn_mfma_f32_16x16x32_bf16(
          af, bfj, (f32x4){0.f, 0.f, 0.f, 0.f}, 0, 0, 0);
    }
    const float* maa_f = (f == 0) ? maa_w : (f == 1) ? maa_k
                        : (f == 2) ? maa_v : (f == 3) ? maa_r : maa_g;
    ushort* dst = (f == 0) ? xw : (f == 1) ? xk
                 : (f == 2) ? xvb : (f == 3) ? xr : xg;
#pragma unroll
    for (int j = 0; j < 8; j++) {
      float mf = maa_f[n0 + j * 16 + lm];
#pragma unroll
      for (int q = 0; q < 4; q++) {
        size_t off = (size_t)(m0 + wid * 16 + rq + q) * C + (n0 + j * 16 + lm);
        dst[off] = f2bf(xh[j][q] + dh[j][q] * (mf + acc[j][q]));
      }
    }
  }
}

// -------------------------------------------- fp32 -> bf16 cvt (5 arrays) --
__global__ __launch_bounds__(256) void k_cvt5(
    const float* __restrict__ s0, const float* __restrict__ s1,
    const float* __restrict__ s2, const float* __restrict__ s3,
    const float* __restrict__ s4,
    ushort* __restrict__ d0, ushort* __restrict__ d1,
    ushort* __restrict__ d2, ushort* __restrict__ d3,
    ushort* __restrict__ d4, int n) {
  const float* s;
  ushort* d;
  switch (blockIdx.y) {
    case 0: s = s0; d = d0; break;
    case 1: s = s1; d = d1; break;
    case 2: s = s2; d = d2; break;
    case 3: s = s3; d = d3; break;
    default: s = s4; d = d4; break;
  }
  int i = (blockIdx.x * 256 + threadIdx.x) * 4;
  if (i >= n) return;
  float4 v = *(const float4*)(s + i);
  ushort4 o;
  o.x = f2bf(v.x); o.y = f2bf(v.y); o.z = f2bf(v.z); o.w = f2bf(v.w);
  *(ushort4*)(d + i) = o;
}

// ----------------------------------------------------- bf16 MFMA GEMM ------
template <int EPI, bool NMASK, bool OBF16>
__global__ __launch_bounds__(256) void k_gemm_bf(
    const ushort* __restrict__ A, const ushort* __restrict__ W,
    const float* __restrict__ bias, void* __restrict__ Cm,
    int M, int N, int K) {
  __shared__ ushort Al[128 * 32];
  __shared__ ushort Bl[128 * 32];
  int tid = threadIdx.x;
  int m0 = blockIdx.y * 128, n0 = blockIdx.x * 128;
  int lane = tid & 63, wave = tid >> 6;
  int wm = (wave >> 1) * 64, wn = (wave & 1) * 64;
  int lm = lane & 15, lk = (lane >> 4) * 8;
  f32x4 acc[4][4];
#pragma unroll
  for (int i = 0; i < 4; i++)
#pragma unroll
    for (int j = 0; j < 4; j++) acc[i][j] = (f32x4){0.f, 0.f, 0.f, 0.f};

  int arow = tid >> 2, achunk = (tid & 3) * 8;
  const ushort* Ag = A + (size_t)(m0 + arow) * K + achunk;
  const ushort* Wg = W + (size_t)(n0 + arow) * K + achunk;
  ushort* Ald = Al + tid * 8;
  ushort* Bld = Bl + tid * 8;

  for (int k0 = 0; k0 < K; k0 += 32) {
    GLDS16(Ag + k0, Ald);
    GLDS16(Ag + (size_t)64 * K + k0, Ald + 2048);
    GLDS16(Wg + k0, Bld);
    GLDS16(Wg + (size_t)64 * K + k0, Bld + 2048);
    __syncthreads();
    bf16x8 af[4], bf[4];
#pragma unroll
    for (int i = 0; i < 4; i++)
      af[i] = *(const bf16x8*)&Al[(wm + i * 16 + lm) * 32 + lk];
#pragma unroll
    for (int j = 0; j < 4; j++)
      bf[j] = *(const bf16x8*)&Bl[(wn + j * 16 + lm) * 32 + lk];
#pragma unroll
    for (int i = 0; i < 4; i++)
#pragma unroll
      for (int j = 0; j < 4; j++)
        acc[i][j] = __builtin_amdgcn_mfma_f32_16x16x32_bf16(
            af[i], bf[j], acc[i][j], 0, 0, 0);
    __syncthreads();
  }
  int rq = (lane >> 4) * 4;
#pragma unroll
  for (int i = 0; i < 4; i++) {
#pragma unroll
    for (int j = 0; j < 4; j++) {
      int gn = n0 + wn + j * 16 + lm;
      if (NMASK && gn >= N) continue;
      float bv = (EPI == EPI_BIAS) ? bias[gn] : 0.f;
#pragma unroll
      for (int q = 0; q < 4; q++) {
        int gm = m0 + wm + i * 16 + rq + q;
        float val = acc[i][j][q];
        if (EPI == EPI_BIAS) val += bv;
        if (EPI == EPI_RELU) val = fmaxf(val, 0.f);
        if (EPI == EPI_TANH) val = tanhf(val);
        if (OBF16) ((ushort*)Cm)[(size_t)gm * N + gn] = f2bf(val);
        else       ((float*)Cm)[(size_t)gm * N + gn] = val;
      }
    }
  }
}

// --------------------------------- batched 4-projection bf16 MFMA GEMM -----
__global__ __launch_bounds__(256) void k_proj4(
    const ushort* __restrict__ A0, const ushort* __restrict__ A1,
    const ushort* __restrict__ A2, const ushort* __restrict__ A3,
    const ushort* __restrict__ W0, const ushort* __restrict__ W1,
    const ushort* __restrict__ W2, const ushort* __restrict__ W3,
    float* __restrict__ C0, float* __restrict__ C1,
    float* __restrict__ C2, float* __restrict__ C3,
    int M, int N, int K) {
  int z = blockIdx.z;
  const ushort* A = (z == 0) ? A0 : (z == 1) ? A1 : (z == 2) ? A2 : A3;
  const ushort* W = (z == 0) ? W0 : (z == 1) ? W1 : (z == 2) ? W2 : W3;
  float* Cm       = (z == 0) ? C0 : (z == 1) ? C1 : (z == 2) ? C2 : C3;
  __shared__ ushort Al[128 * 32];
  __shared__ ushort Bl[128 * 32];
  int tid = threadIdx.x;
  int m0 = blockIdx.y * 128, n0 = blockIdx.x * 128;
  int lane = tid & 63, wave = tid >> 6;
  int wm = (wave >> 1) * 64, wn = (wave & 1) * 64;
  int lm = lane & 15, lk = (lane >> 4) * 8;
  f32x4 acc[4][4];
#pragma unroll
  for (int i = 0; i < 4; i++)
#pragma unroll
    for (int j = 0; j < 4; j++) acc[i][j] = (f32x4){0.f, 0.f, 0.f, 0.f};

  int arow = tid >> 2, achunk = (tid & 3) * 8;
  const ushort* Ag = A + (size_t)(m0 + arow) * K + achunk;
  const ushort* Wg = W + (size_t)(n0 + arow) * K + achunk;
  ushort* Ald = Al + tid * 8;
  ushort* Bld = Bl + tid * 8;

  for (int k0 = 0; k0 < K; k0 += 32) {
    GLDS16(Ag + k0, Ald);
    GLDS16(Ag + (size_t)64 * K + k0, Ald + 2048);
    GLDS16(Wg + k0, Bld);
    GLDS16(Wg + (size_t)64 * K + k0, Bld + 2048);
    __syncthreads();
    bf16x8 af[4], bf[4];
#pragma unroll
    for (int i = 0; i < 4; i++)
      af[i] = *(const bf16x8*)&Al[(wm + i * 16 + lm) * 32 + lk];
#pragma unroll
    for (int j = 0; j < 4; j++)
      bf[j] = *(const bf16x8*)&Bl[(wn + j * 16 + lm) * 32 + lk];
#pragma unroll
    for (int i = 0; i < 4; i++)
#pragma unroll
      for (int j = 0; j < 4; j++)
        acc[i][j] = __builtin_amdgcn_mfma_f32_16x16x32_bf16(
            af[i], bf[j], acc[i][j], 0, 0, 0);
    __syncthreads();
  }
  bool relu = (z == 3);
  int rq = (lane >> 4) * 4;
#pragma unroll
  for (int i = 0; i < 4; i++) {
#pragma unroll
    for (int j = 0; j < 4; j++) {
      int gn = n0 + wn + j * 16 + lm;
#pragma unroll
      for (int q = 0; q < 4; q++) {
        int gm = m0 + wm + i * 16 + rq + q;
        float val = acc[i][j][q];
        if (relu) val = fmaxf(val, 0.f);
        Cm[(size_t)gm * N + gn] = val;
      }
    }
  }
}

// ------------------------------------------------- chunked WKV: phase pre --
// pdiag via LDS stage + per-row sum (replaces 64x serial 6-deep shfl chains).
__global__ __launch_bounds__(64) void k_wkv_pre(
    const float* __restrict__ r, const float* __restrict__ k,
    const float* __restrict__ w, const float* __restrict__ u,
    float* __restrict__ rt, float* __restrict__ kt,
    float* __restrict__ aL, float* __restrict__ pdiag,
    int B, int T, int C, int H, int L) {
  __shared__ float pls[64 * 65];
  int nch = T / L;
  int blk = blockIdx.x;
  int bh = blk / nch, c = blk - bh * nch;
  int b = bh / H, h = bh - b * H;
  int j = threadIdx.x;
  float uj = u[h * 64 + j];
  float cum = 0.f;
  long base = ((long)b * T + (long)c * L) * C + h * 64 + j;
  for (int tau = 0; tau < L; tau++) {
    long off = base + (long)tau * C;
    float wv = w[off];
    float rv = r[off];
    float kv = k[off];
    float e = expf(wv);
    rt[off] = rv * expf(-cum);
    cum += e;
    kt[off] = kv * expf(cum);
    pls[tau * 65 + j] = rv * uj * kv;
  }
  aL[((long)bh * nch + c) * 64 + j] = expf(-cum);
  __syncthreads();
  float s0 = 0.f, s1 = 0.f, s2 = 0.f, s3 = 0.f;
#pragma unroll
  for (int q = 0; q < 16; q++) {
    float4 p4 = *(const float4*)(pls + j * 65 + q * 4);
    s0 += p4.x; s1 += p4.y; s2 += p4.z; s3 += p4.w;
  }
  pdiag[(long)bh * T + c * L + j] = (s0 + s1) + (s2 + s3);
}

// --------------------------------------- chunked WKV: per-chunk KV outer ---
// GLDS staging (no VGPR roundtrip), unpadded 16KB tiles.
__global__ __launch_bounds__(256) void k_wkv_kv(
    const float* __restrict__ kt, const float* __restrict__ v,
    float* __restrict__ kvb, int B, int T, int C, int H, int L) {
  int nch = T / L;
  int blk = blockIdx.x;
  int bh = blk / nch, c = blk - bh * nch;
  int b = bh / H, h = bh - b * H;
  __shared__ float Ks[64 * 64];
  __shared__ float Vs[64 * 64];
  int tid = threadIdx.x;
  int lane = tid & 63, jg = tid >> 6;
  long cbase = ((long)b * T + (long)c * L) * C + h * 64;
#pragma unroll
  for (int i = 0; i < 4; i++) {
    int chunk = jg * 4 + i;
    int row = chunk * 4 + (lane >> 4);
    int cq = lane & 15;
    GLDS16(kt + cbase + (long)row * C + cq * 4, Ks + chunk * 256);
    GLDS16(v + cbase + (long)row * C + cq * 4, Vs + chunk * 256);
  }
  __syncthreads();
  float acc[16];
#pragma unroll
  for (int q = 0; q < 16; q++) acc[q] = 0.f;
  for (int s = 0; s < 64; s++) {
    float vi = Vs[s * 64 + lane];
#pragma unroll
    for (int q4 = 0; q4 < 4; q4++) {
      float4 kk = *(const float4*)(Ks + s * 64 + jg * 16 + q4 * 4);
      acc[q4 * 4 + 0] = fmaf(kk.x, vi, acc[q4 * 4 + 0]);
      acc[q4 * 4 + 1] = fmaf(kk.y, vi, acc[q4 * 4 + 1]);
      acc[q4 * 4 + 2] = fmaf(kk.z, vi, acc[q4 * 4 + 2]);
      acc[q4 * 4 + 3] = fmaf(kk.w, vi, acc[q4 * 4 + 3]);
    }
  }
  float* out = kvb + ((long)bh * nch + c) * 4096;
#pragma unroll
  for (int q = 0; q < 16; q++) out[(jg * 16 + q) * 64 + lane] = acc[q];
}

// ---------------------------------------- chunked WKV: state prefix scan ---
// Elementwise-independent across the 4096 state entries -> 16x more blocks.
__global__ __launch_bounds__(256) void k_wkv_scan(
    const float* __restrict__ kvb, const float* __restrict__ aL,
    float* __restrict__ Scb, int nch) {
  int bh = blockIdx.x >> 4;
  int e = ((blockIdx.x & 15) << 8) + threadIdx.x;   // 0..4095
  float S = 0.f;
  for (int c = 0; c < nch; c++) {
    long cb = ((long)bh * nch + c) * 4096 + e;
    Scb[cb] = S;
    S = aL[((long)bh * nch + c) * 64 + (e >> 6)] * (S + kvb[cb]);
  }
}

// ------------- chunked WKV: intra + inter + groupnorm*gate (fused) ---------
// Two unpadded 16KB tiles (32KB total -> 4-5 blocks/CU):
//   TA: Rt(src-swizzled) -> V -> Rt^T     TB: Kt -> P^T (in place, wave-own)
// All staging via global_load_lds; rreg read applies the same XOR swizzle
// the GLDS source applied (LDS stays linear, per m173). Rt^T write uses a
// wave-uniform static switch so every rreg index is compile-time (rule #20).
__global__ __launch_bounds__(256, 4) void k_wkv_intra(
    const float* __restrict__ rt, const float* __restrict__ kt,
    const float* __restrict__ v, const float* __restrict__ pdiag,
    const float* __restrict__ Scb, const float* __restrict__ g,
    const float* __restrict__ ln_w, const float* __restrict__ ln_b,
    ushort* __restrict__ z, int B, int T, int C, int H, int L) {
  int nch = T / L;
  int blk = blockIdx.x;
  int bh = blk / nch, c = blk - bh * nch;
  int b = bh / H, h = bh - b * H;
  __shared__ float TA[64 * 64];
  __shared__ float TB[64 * 64];
  int tid = threadIdx.x;
  int lane = tid & 63, wid = tid >> 6;
  int tau = lane;
  long cbase = ((long)b * T + (long)c * L) * C + h * 64;
  const float* scp = Scb + ((long)bh * nch + c) * 4096;

  // --- stage: Rt (swizzled source) -> TA, Kt -> TB ---
#pragma unroll
  for (int i = 0; i < 4; i++) {
    int chunk = wid * 4 + i;
    int row = chunk * 4 + (lane >> 4);
    int cq = lane & 15;
    GLDS16(rt + cbase + (long)row * C + ((cq ^ (row & 15)) * 4),
           TA + chunk * 256);
    GLDS16(kt + cbase + (long)row * C + cq * 4, TB + chunk * 256);
  }
  __syncthreads();   // Rt+Kt resident (barrier drains vmcnt)

  // --- rreg: full Rt row per lane, via the inverse swizzle (4-way, cheap) --
  float4 rreg[16];
#pragma unroll
  for (int q = 0; q < 16; q++)
    rreg[q] = *(const float4*)(TA + tau * 64 + ((q ^ (tau & 15)) * 4));
  float pd = pdiag[(long)bh * T + c * L + tau];
  __syncthreads();   // all rreg reads done; TA reusable

  // --- stage V -> TA (lands during phase 1) ---
#pragma unroll
  for (int i = 0; i < 4; i++) {
    int chunk = wid * 4 + i;
    int row = chunk * 4 + (lane >> 4);
    GLDS16(v + cbase + (long)row * C + (lane & 15) * 4, TA + chunk * 256);
  }

  // --- phase 1: P^T row s over Kt row s (wave-own rows 16*wid..16*wid+15) --
#pragma unroll 2
  for (int ss = 0; ss < 16; ss++) {
    int s = wid * 16 + ss;
    float a0 = 0.f, a1 = 0.f, a2 = 0.f, a3 = 0.f;
#pragma unroll
    for (int q = 0; q < 16; q++) {
      float4 kk = *(const float4*)(TB + s * 64 + q * 4);   // broadcast
      a0 = fmaf(rreg[q].x, kk.x, a0);
      a1 = fmaf(rreg[q].y, kk.y, a1);
      a2 = fmaf(rreg[q].z, kk.z, a2);
      a3 = fmaf(rreg[q].w, kk.w, a3);
    }
    float a = (a0 + a1) + (a2 + a3);
    float val = (s < tau) ? a : (s == tau ? pd : 0.f);
    TB[s * 64 + tau] = val;
  }
  __syncthreads();   // P^T complete everywhere; V resident

  // --- pass A: acc += P^T ⊗ V ---
  int row0 = wid * 16 + ((lane >> 4) << 2);   // 4 consecutive output rows
  int c0 = (lane & 15) * 4;                   // 4 consecutive channels
  float4 acc0 = {0.f, 0.f, 0.f, 0.f};
  float4 acc1 = {0.f, 0.f, 0.f, 0.f};
  float4 acc2 = {0.f, 0.f, 0.f, 0.f};
  float4 acc3 = {0.f, 0.f, 0.f, 0.f};
#define FMA1(A, P, V4)                 \
  A.x = fmaf(P, V4.x, A.x);            \
  A.y = fmaf(P, V4.y, A.y);            \
  A.z = fmaf(P, V4.z, A.z);            \
  A.w = fmaf(P, V4.w, A.w);
#pragma unroll 4
  for (int j = 0; j < 64; j++) {
    float4 pp = *(const float4*)(TB + j * 64 + row0);   // 16-lane multicast
    float4 vv = *(const float4*)(TA + j * 64 + c0);     // 2-way (free)
    FMA1(acc0, pp.x, vv);
    FMA1(acc1, pp.y, vv);
    FMA1(acc2, pp.z, vv);
    FMA1(acc3, pp.w, vv);
  }
  __syncthreads();   // V reads done; TA reusable

  // --- Rt^T -> TA (wave wid owns q-rows [16*wid, 16*wid+16)) ---
#define WRQ(SG)                                                          \
  {                                                                      \
    _Pragma("unroll") for (int qq = 0; qq < 16; qq++) {                  \
      const float* rp = (const float*)&rreg[(SG) * 4 + (qq >> 2)];       \
      TA[((SG) * 16 + qq) * 64 + tau] = rp[qq & 3];                      \
    }                                                                    \
  }
  if (wid == 0)      WRQ(0)
  else if (wid == 1) WRQ(1)
  else if (wid == 2) WRQ(2)
  else               WRQ(3)
#undef WRQ
  __syncthreads();

  // --- pass B: acc += Rt^T ⊗ S_prev (S from global, coalesced, L1 x4) ---
#pragma unroll 4
  for (int j = 0; j < 64; j++) {
    float4 rr = *(const float4*)(TA + j * 64 + row0);   // 16-lane multicast
    float4 ssv = *(const float4*)(scp + j * 64 + c0);
    FMA1(acc0, rr.x, ssv);
    FMA1(acc1, rr.y, ssv);
    FMA1(acc2, rr.z, ssv);
    FMA1(acc3, rr.w, ssv);
  }
#undef FMA1

  // ---- fused groupnorm (per row over this head's 64 channels) * gate ----
  float4 lw4 = *(const float4*)(ln_w + h * 64 + c0);
  float4 lb4 = *(const float4*)(ln_b + h * 64 + c0);
#define GNROW(A, m)                                                        \
  {                                                                        \
    float s1 = (A.x + A.y) + (A.z + A.w);                                  \
    s1 += __shfl_xor(s1, 1, 64);                                           \
    s1 += __shfl_xor(s1, 2, 64);                                           \
    s1 += __shfl_xor(s1, 4, 64);                                           \
    s1 += __shfl_xor(s1, 8, 64);                                           \
    float mu = s1 * (1.f / 64.f);                                          \
    float4 dd;                                                             \
    dd.x = A.x - mu; dd.y = A.y - mu; dd.z = A.z - mu; dd.w = A.w - mu;    \
    float s2 = (dd.x * dd.x + dd.y * dd.y) + (dd.z * dd.z + dd.w * dd.w);  \
    s2 += __shfl_xor(s2, 1, 64);                                           \
    s2 += __shfl_xor(s2, 2, 64);                                           \
    s2 += __shfl_xor(s2, 4, 64);                                           \
    s2 += __shfl_xor(s2, 8, 64);                                           \
    float rstd = rsqrtf(s2 * (1.f / 64.f) + 1e-5f);                        \
    long off = cbase + (long)(row0 + m) * C + c0;                          \
    float4 g4 = *(const float4*)(g + off);                                 \
    ushort4 ob;                                                            \
    ob.x = f2bf((dd.x * rstd * lw4.x + lb4.x) * g4.x);                     \
    ob.y = f2bf((dd.y * rstd * lw4.y + lb4.y) * g4.y);                     \
    ob.z = f2bf((dd.z * rstd * lw4.z + lb4.z) * g4.z);                     \
    ob.w = f2bf((dd.w * rstd * lw4.w + lb4.w) * g4.w);                     \
    *(ushort4*)(z + off) = ob;                                             \
  }
  GNROW(acc0, 0)
  GNROW(acc1, 1)
  GNROW(acc2, 2)
  GNROW(acc3, 3)
#undef GNROW
}

// ---------------------------------------------------------------- launch ---
extern "C" void kernel_launch(void* const* d_in, const int* in_sizes, int n_in,
                              void* d_out, int out_size, void* d_ws, size_t ws_size,
                              hipStream_t stream) {
  const int B = 8, T = 1024, C = 768, H = 12, ph = 32, pw = 32;
  const int M = B * T;
  const int L = 64, NCH = T / L;

  const float* x        = (const float*)d_in[0];
  const float* W_r      = (const float*)d_in[1];
  const float* W_k      = (const float*)d_in[2];
  const float* W_v      = (const float*)d_in[3];
  const float* W_g      = (const float*)d_in[4];
  const float* W_o      = (const float*)d_in[5];
  const float* maa_x    = (const float*)d_in[6];
  const float* maa_w    = (const float*)d_in[7];
  const float* maa_k    = (const float*)d_in[8];
  const float* maa_v    = (const float*)d_in[9];
  const float* maa_r    = (const float*)d_in[10];
  const float* maa_g    = (const float*)d_in[11];
  const float* maa_w1   = (const float*)d_in[12];
  const float* maa_w2   = (const float*)d_in[13];
  const float* time_dec = (const float*)d_in[14];
  const float* dec_w1   = (const float*)d_in[15];
  const float* dec_w2   = (const float*)d_in[16];
  const float* faaaa    = (const float*)d_in[17];
  const float* ln_w     = (const float*)d_in[18];
  const float* ln_b     = (const float*)d_in[19];

  float* ws = (float*)d_ws;
  const size_t S = (size_t)M * C;
  float* F0 = ws + 0 * S;   // xx -> r -> kvb
  float* F1 = ws + 1 * S;   // xxx_bf -> k -> Scb
  float* F2 = ws + 2 * S;   // xw_bf -> w -> Kt (in place)
  float* F3 = ws + 3 * S;   // v
  float* F4 = ws + 4 * S;   // g
  float* F5 = ws + 5 * S;   // xr_bf | xk_bf -> Rt (fp32)
  float* F6 = ws + 6 * S;   // xv_bf | xg_bf -> z_bf
  float* t5    = ws + 7 * S;            // [M,160] bf16 t5b -> bf16 W_r..W_g
  float* t6    = t5 + (size_t)M * 160;  // bf16 W_o + maa1T + decT
  float* aLb   = t6 + (size_t)M * 64;
  float* pdiag = aLb + (size_t)B * H * NCH * 64;
  float* dec_t = pdiag + (size_t)B * H * T;   // [M,64] t_bf + w2T scratch

  ushort* xxx_bf = (ushort*)F1;
  ushort* xw_bf = (ushort*)F2;
  ushort* xr_bf = (ushort*)F5;
  ushort* xk_bf = xr_bf + S;
  ushort* xv_bf = (ushort*)F6;
  ushort* xg_bf = xv_bf + S;
  ushort* z_bf  = (ushort*)F6;
  ushort* t5b   = (ushort*)t5;          // [M,160] bf16
  ushort* t_bf  = (ushort*)dec_t;       // [M,64] bf16
  ushort* w2T   = t_bf + (size_t)M * 64;  // [768,160] bf16 (dead after mix5)
  float* kvb = F0;
  float* Scb = F1;
  const int WSZ = C * C;
  ushort* wr_bf = (ushort*)t5;
  ushort* wk_bf = wr_bf + WSZ;
  ushort* wv_bf = wk_bf + WSZ;
  ushort* wg_bf = wv_bf + WSZ;
  ushort* wo_bf = (ushort*)t6;
  ushort* maa1T = wo_bf + WSZ;          // [256,768]
  ushort* w1dT  = maa1T + 256 * 768;    // [128,768]
  ushort* w2dT  = w1dT + 128 * 768;     // [768,64]

  // 1. qshift (xx fp32, xxx bf16)
  {
    long total = (long)M * C;
    k_qshift<<<(int)((total + 255) / 256), 256, 0, stream>>>(
        x, maa_x, F0, xxx_bf, B, T, C, ph, pw);
  }
  // 2. weight transposes -> bf16; t5b = tanh(xxx @ maa_w1) via MFMA (bf16)
  {
    dim3 gt(3, 256);
    k_w1t<<<gt, 256, 0, stream>>>(maa_w1, maa1T);
    k_w2t<<<768 * 160 / 256, 256, 0, stream>>>(maa_w2, w2T);
    k_decT<<<(128 * 768 + 768 * 64) / 256, 256, 0, stream>>>(
        dec_w1, dec_w2, w1dT, w2dT);
    dim3 grid(2, M / 128);
    k_gemm_bf<EPI_TANH, true, true><<<grid, 256, 0, stream>>>(
        xxx_bf, maa1T, nullptr, t5b, M, 160, C);
  }
  // 3. mix5 on MFMA (all outputs bf16)
  {
    dim3 grid(C / 128, M / 64);
    k_mix5m<<<grid, 256, 0, stream>>>(t5b, w2T, x, F0, maa_w, maa_k, maa_v,
                                      maa_r, maa_g, xw_bf, xk_bf, xv_bf, xr_bf,
                                      xg_bf, C);
  }
  // 4. weight conversion (t5b data dead now)
  {
    dim3 grid((WSZ / 4 + 255) / 256, 5);
    k_cvt5<<<grid, 256, 0, stream>>>(W_r, W_k, W_v, W_g, W_o,
                                     wr_bf, wk_bf, wv_bf, wg_bf, wo_bf, WSZ);
  }
  // 5. big projections: ONE batched bf16 MFMA dispatch (grid.z = 4)
  {
    dim3 grid(C / 128, M / 128, 4);
    k_proj4<<<grid, 256, 0, stream>>>(xr_bf, xk_bf, xv_bf, xg_bf,
                                      wr_bf, wk_bf, wv_bf, wg_bf,
                                      F0, F1, F3, F4, M, C, C);
  }
  // 6. decay path on MFMA
  {
    dim3 g1(1, M / 128);
    k_gemm_bf<EPI_TANH, true, true><<<g1, 256, 0, stream>>>(
        xw_bf, w1dT, nullptr, t_bf, M, 64, C);
    dim3 g2(C / 128, M / 128);
    k_gemm_bf<EPI_BIAS, false, false><<<g2, 256, 0, stream>>>(
        t_bf, w2dT, time_dec, F2, M, C, 64);
  }
  // 7. chunked wkv6: pre -> kv -> scan -> intra(+GN+gate -> z bf16)
  k_wkv_pre<<<B * H * NCH, 64, 0, stream>>>(F0, F1, F2, faaaa, F5, F2,
                                            aLb, pdiag, B, T, C, H, L);
  k_wkv_kv<<<B * H * NCH, 256, 0, stream>>>(F2, F3, kvb, B, T, C, H, L);
  k_wkv_scan<<<B * H * 16, 256, 0, stream>>>(kvb, aLb, Scb, NCH);
  k_wkv_intra<<<B * H * NCH, 256, 0, stream>>>(F5, F2, F3, pdiag, Scb, F4,
                                               ln_w, ln_b, z_bf, B, T, C, H, L);
  // 8. out = z @ W_o^T (bf16 MFMA)
  {
    dim3 grid(C / 128, M / 128);
    k_gemm_bf<EPI_NONE, false, false><<<grid, 256, 0, stream>>>(
        z_bf, wo_bf, nullptr, (float*)d_out, M, C, C);
  }
}

// Round 4
// 441.974 us; speedup vs baseline: 1.2159x; 1.0129x over previous
//
#include <hip/hip_runtime.h>
#include <math.h>

// ---------------------------------------------------------------------------
// TimeMix (RWKV-6 vision block) — round 13: GEMM family (k_proj4, k_gemm_bf)
// rebuilt with BK=64 (128B LDS rows) + XOR chunk swizzle (bank-conflict-free
// ds_read_b128, rule #21 both-sides form) + bijective XCD block swizzle for
// L2 A-panel reuse. B=8, T=1024, C=768, H=12.
// ---------------------------------------------------------------------------

#define EPI_NONE 0
#define EPI_TANH 1
#define EPI_RELU 2
#define EPI_BIAS 3

typedef float f32x4 __attribute__((ext_vector_type(4)));
typedef __bf16 bf16x8 __attribute__((ext_vector_type(8)));

__device__ __forceinline__ ushort f2bf(float x) {
  unsigned u = __float_as_uint(x);
  return (ushort)((u + 0x7fffu + ((u >> 16) & 1u)) >> 16);
}

#define GLDS16(gp, lp)                                                   \
  __builtin_amdgcn_global_load_lds(                                      \
      (const __attribute__((address_space(1))) void*)(gp),               \
      (__attribute__((address_space(3))) void*)(lp), 16, 0, 0)

// ---------------------------------------------------------------- qshift ---
__global__ __launch_bounds__(256) void k_qshift(
    const float* __restrict__ x, const float* __restrict__ maa_x,
    float* __restrict__ xx, ushort* __restrict__ xxx_bf,
    int B, int T, int C, int ph, int pw) {
  long idx = (long)blockIdx.x * blockDim.x + threadIdx.x;
  long total = (long)B * T * C;
  if (idx >= total) return;
  int c = (int)(idx % C);
  long bt = idx / C;
  int t = (int)(bt % T);
  int quarter = (c & 63) >> 4;
  int hh = t / pw;
  int ww = t - hh * pw;
  long rowbase = (bt - t) * C;
  float sval = 0.f;
  int st = -1;
  if (quarter == 0)      { if (ww >= 1)      st = t - 1;  }
  else if (quarter == 1) { if (ww < pw - 1)  st = t + 1;  }
  else if (quarter == 2) { if (hh >= 1)      st = t - pw; }
  else                   { if (hh < ph - 1)  st = t + pw; }
  if (st >= 0) sval = x[rowbase + (long)st * C + c];
  float xval = x[idx];
  float d = sval - xval;
  xx[idx] = d;
  xxx_bf[idx] = f2bf(xval + d * maa_x[c]);
}

// ------------------------------------- maa_w1 transpose+convert to bf16 ----
__global__ __launch_bounds__(256) void k_w1t(
    const float* __restrict__ w1, ushort* __restrict__ out) {
  int n = blockIdx.y;
  int k = blockIdx.x * 256 + threadIdx.x;
  float v = (n < 160) ? w1[(size_t)k * 160 + n] : 0.f;
  out[(size_t)n * 768 + k] = f2bf(v);
}

// ------------------------- maa_w2 transpose+convert to bf16 [768][160] -----
__global__ __launch_bounds__(256) void k_w2t(
    const float* __restrict__ w2, ushort* __restrict__ w2T) {
  int idx = blockIdx.x * 256 + threadIdx.x;   // 0 .. 768*160-1
  int c = idx / 160, kk = idx - c * 160;
  w2T[idx] = f2bf(w2[(size_t)kk * 768 + c]);
}

// -------------------------- dec_w1 / dec_w2 transpose+convert to bf16 ------
__global__ __launch_bounds__(256) void k_decT(
    const float* __restrict__ w1, const float* __restrict__ w2,
    ushort* __restrict__ w1dT, ushort* __restrict__ w2dT) {
  int idx = blockIdx.x * 256 + threadIdx.x;
  if (idx < 128 * 768) {
    int n = idx / 768, k = idx - n * 768;
    float v = (n < 64) ? w1[(size_t)k * 64 + n] : 0.f;
    w1dT[idx] = f2bf(v);
  } else {
    int j = idx - 128 * 768;
    int n = j >> 6, k = j & 63;
    w2dT[j] = f2bf(w2[(size_t)k * 768 + n]);
  }
}

// --------------------------- mix5 on MFMA, no LDS, no barriers -------------
__global__ __launch_bounds__(256) void k_mix5m(
    const ushort* __restrict__ t5b, const ushort* __restrict__ w2T,
    const float* __restrict__ x, const float* __restrict__ xx,
    const float* __restrict__ maa_w, const float* __restrict__ maa_k,
    const float* __restrict__ maa_v, const float* __restrict__ maa_r,
    const float* __restrict__ maa_g,
    ushort* __restrict__ xw, ushort* __restrict__ xk, ushort* __restrict__ xvb,
    ushort* __restrict__ xr, ushort* __restrict__ xg, int C) {
  int tid = threadIdx.x;
  int lane = tid & 63, wid = tid >> 6;
  int m0 = blockIdx.y * 64, n0 = blockIdx.x * 128;
  int lm = lane & 15, lk = (lane >> 4) * 8;
  int rq = (lane >> 4) * 4;
  const ushort* ap = t5b + (size_t)(m0 + wid * 16 + lm) * 160 + lk;

  float xh[8][4], dh[8][4];
#pragma unroll
  for (int j = 0; j < 8; j++)
#pragma unroll
    for (int q = 0; q < 4; q++) {
      size_t off = (size_t)(m0 + wid * 16 + rq + q) * C + (n0 + j * 16 + lm);
      xh[j][q] = x[off];
      dh[j][q] = xx[off];
    }

#pragma unroll
  for (int f = 0; f < 5; f++) {
    bf16x8 af = *(const bf16x8*)(ap + f * 32);
    f32x4 acc[8];
#pragma unroll
    for (int j = 0; j < 8; j++) {
      bf16x8 bfj = *(const bf16x8*)(w2T +
          (size_t)(n0 + j * 16 + lm) * 160 + f * 32 + lk);
      acc[j] = __builtin_amdgcn_mfma_f32_16x16x32_bf16(
          af, bfj, (f32x4){0.f, 0.f, 0.f, 0.f}, 0, 0, 0);
    }
    const float* maa_f = (f == 0) ? maa_w : (f == 1) ? maa_k
                        : (f == 2) ? maa_v : (f == 3) ? maa_r : maa_g;
    ushort* dst = (f == 0) ? xw : (f == 1) ? xk
                 : (f == 2) ? xvb : (f == 3) ? xr : xg;
#pragma unroll
    for (int j = 0; j < 8; j++) {
      float mf = maa_f[n0 + j * 16 + lm];
#pragma unroll
      for (int q = 0; q < 4; q++) {
        size_t off = (size_t)(m0 + wid * 16 + rq + q) * C + (n0 + j * 16 + lm);
        dst[off] = f2bf(xh[j][q] + dh[j][q] * (mf + acc[j][q]));
      }
    }
  }
}

// -------------------------------------------- fp32 -> bf16 cvt (5 arrays) --
__global__ __launch_bounds__(256) void k_cvt5(
    const float* __restrict__ s0, const float* __restrict__ s1,
    const float* __restrict__ s2, const float* __restrict__ s3,
    const float* __restrict__ s4,
    ushort* __restrict__ d0, ushort* __restrict__ d1,
    ushort* __restrict__ d2, ushort* __restrict__ d3,
    ushort* __restrict__ d4, int n) {
  const float* s;
  ushort* d;
  switch (blockIdx.y) {
    case 0: s = s0; d = d0; break;
    case 1: s = s1; d = d1; break;
    case 2: s = s2; d = d2; break;
    case 3: s = s3; d = d3; break;
    default: s = s4; d = d4; break;
  }
  int i = (blockIdx.x * 256 + threadIdx.x) * 4;
  if (i >= n) return;
  float4 v = *(const float4*)(s + i);
  ushort4 o;
  o.x = f2bf(v.x); o.y = f2bf(v.y); o.z = f2bf(v.z); o.w = f2bf(v.w);
  *(ushort4*)(d + i) = o;
}

// ----------------------------------------------------- bf16 MFMA GEMM ------
// BK=64 (128B LDS rows). Staging: GLDS dest linear, global source column-
// chunk XOR-swizzled by (row&7); fragment read applies the same XOR ->
// 8 consecutive rows hit 8 distinct 4-bank sets (2-way = free). XCD-swizzled
// flattened block id for L2 A-panel reuse (grids are %8==0).
template <int EPI, bool NMASK, bool OBF16>
__global__ __launch_bounds__(256) void k_gemm_bf(
    const ushort* __restrict__ A, const ushort* __restrict__ W,
    const float* __restrict__ bias, void* __restrict__ Cm,
    int M, int N, int K) {
  __shared__ ushort Al[128 * 64];
  __shared__ ushort Bl[128 * 64];
  int nwg = gridDim.x * gridDim.y;
  int bid = blockIdx.y * gridDim.x + blockIdx.x;
  int swz = (nwg & 7) == 0 ? ((bid & 7) * (nwg >> 3) + (bid >> 3)) : bid;
  int bx = swz % gridDim.x, by = swz / gridDim.x;
  int m0 = by * 128, n0 = bx * 128;
  int tid = threadIdx.x;
  int lane = tid & 63, wave = tid >> 6;
  int wm = (wave >> 1) * 64, wn = (wave & 1) * 64;
  int lm = lane & 15, g = lane >> 4;
  f32x4 acc[4][4];
#pragma unroll
  for (int i = 0; i < 4; i++)
#pragma unroll
    for (int j = 0; j < 4; j++) acc[i][j] = (f32x4){0.f, 0.f, 0.f, 0.f};

  for (int k0 = 0; k0 < K; k0 += 64) {
#pragma unroll
    for (int i = 0; i < 4; i++) {
      int cid = tid + i * 256;             // 0..1023 16B-chunks
      int row = cid >> 3, p = cid & 7;
      int cq = p ^ (row & 7);
      GLDS16(A + (size_t)(m0 + row) * K + k0 + cq * 8, Al + cid * 8);
      GLDS16(W + (size_t)(n0 + row) * K + k0 + cq * 8, Bl + cid * 8);
    }
    __syncthreads();
#pragma unroll
    for (int s = 0; s < 2; s++) {
      bf16x8 af[4], bf[4];
#pragma unroll
      for (int i = 0; i < 4; i++) {
        int r = wm + i * 16 + lm;
        af[i] = *(const bf16x8*)&Al[r * 64 + (((s * 4 + g) ^ (r & 7)) * 8)];
        int rb = wn + i * 16 + lm;
        bf[i] = *(const bf16x8*)&Bl[rb * 64 + (((s * 4 + g) ^ (rb & 7)) * 8)];
      }
#pragma unroll
      for (int i = 0; i < 4; i++)
#pragma unroll
        for (int j = 0; j < 4; j++)
          acc[i][j] = __builtin_amdgcn_mfma_f32_16x16x32_bf16(
              af[i], bf[j], acc[i][j], 0, 0, 0);
    }
    __syncthreads();
  }
  int rq = (lane >> 4) * 4;
#pragma unroll
  for (int i = 0; i < 4; i++) {
#pragma unroll
    for (int j = 0; j < 4; j++) {
      int gn = n0 + wn + j * 16 + lm;
      if (NMASK && gn >= N) continue;
      float bv = (EPI == EPI_BIAS) ? bias[gn] : 0.f;
#pragma unroll
      for (int q = 0; q < 4; q++) {
        int gm = m0 + wm + i * 16 + rq + q;
        float val = acc[i][j][q];
        if (EPI == EPI_BIAS) val += bv;
        if (EPI == EPI_RELU) val = fmaxf(val, 0.f);
        if (EPI == EPI_TANH) val = tanhf(val);
        if (OBF16) ((ushort*)Cm)[(size_t)gm * N + gn] = f2bf(val);
        else       ((float*)Cm)[(size_t)gm * N + gn] = val;
      }
    }
  }
}

// --------------------------------- batched 4-projection bf16 MFMA GEMM -----
// Same BK=64 + XOR-swizzle structure; 1D grid (1536) with XCD swizzle,
// decomposed z-major / my / nx-fastest for per-XCD A-panel + W L2 reuse.
__global__ __launch_bounds__(256) void k_proj4(
    const ushort* __restrict__ A0, const ushort* __restrict__ A1,
    const ushort* __restrict__ A2, const ushort* __restrict__ A3,
    const ushort* __restrict__ W0, const ushort* __restrict__ W1,
    const ushort* __restrict__ W2, const ushort* __restrict__ W3,
    float* __restrict__ C0, float* __restrict__ C1,
    float* __restrict__ C2, float* __restrict__ C3,
    int M, int N, int K) {
  int nwg = gridDim.x;                       // 1536, %8==0
  int bid = blockIdx.x;
  int swz = (bid & 7) * (nwg >> 3) + (bid >> 3);
  int nxt = N / 128;                         // 6
  int per_z = (M / 128) * nxt;               // 384
  int z = swz / per_z;
  int rem = swz - z * per_z;
  int my = rem / nxt, nx = rem - my * nxt;
  const ushort* A = (z == 0) ? A0 : (z == 1) ? A1 : (z == 2) ? A2 : A3;
  const ushort* W = (z == 0) ? W0 : (z == 1) ? W1 : (z == 2) ? W2 : W3;
  float* Cm       = (z == 0) ? C0 : (z == 1) ? C1 : (z == 2) ? C2 : C3;
  __shared__ ushort Al[128 * 64];
  __shared__ ushort Bl[128 * 64];
  int tid = threadIdx.x;
  int m0 = my * 128, n0 = nx * 128;
  int lane = tid & 63, wave = tid >> 6;
  int wm = (wave >> 1) * 64, wn = (wave & 1) * 64;
  int lm = lane & 15, g = lane >> 4;
  f32x4 acc[4][4];
#pragma unroll
  for (int i = 0; i < 4; i++)
#pragma unroll
    for (int j = 0; j < 4; j++) acc[i][j] = (f32x4){0.f, 0.f, 0.f, 0.f};

  for (int k0 = 0; k0 < K; k0 += 64) {
#pragma unroll
    for (int i = 0; i < 4; i++) {
      int cid = tid + i * 256;
      int row = cid >> 3, p = cid & 7;
      int cq = p ^ (row & 7);
      GLDS16(A + (size_t)(m0 + row) * K + k0 + cq * 8, Al + cid * 8);
      GLDS16(W + (size_t)(n0 + row) * K + k0 + cq * 8, Bl + cid * 8);
    }
    __syncthreads();
#pragma unroll
    for (int s = 0; s < 2; s++) {
      bf16x8 af[4], bf[4];
#pragma unroll
      for (int i = 0; i < 4; i++) {
        int r = wm + i * 16 + lm;
        af[i] = *(const bf16x8*)&Al[r * 64 + (((s * 4 + g) ^ (r & 7)) * 8)];
        int rb = wn + i * 16 + lm;
        bf[i] = *(const bf16x8*)&Bl[rb * 64 + (((s * 4 + g) ^ (rb & 7)) * 8)];
      }
#pragma unroll
      for (int i = 0; i < 4; i++)
#pragma unroll
        for (int j = 0; j < 4; j++)
          acc[i][j] = __builtin_amdgcn_mfma_f32_16x16x32_bf16(
              af[i], bf[j], acc[i][j], 0, 0, 0);
    }
    __syncthreads();
  }
  bool relu = (z == 3);
  int rq = (lane >> 4) * 4;
#pragma unroll
  for (int i = 0; i < 4; i++) {
#pragma unroll
    for (int j = 0; j < 4; j++) {
      int gn = n0 + wn + j * 16 + lm;
#pragma unroll
      for (int q = 0; q < 4; q++) {
        int gm = m0 + wm + i * 16 + rq + q;
        float val = acc[i][j][q];
        if (relu) val = fmaxf(val, 0.f);
        Cm[(size_t)gm * N + gn] = val;
      }
    }
  }
}

// ------------------------------------------------- chunked WKV: phase pre --
__global__ __launch_bounds__(64) void k_wkv_pre(
    const float* __restrict__ r, const float* __restrict__ k,
    const float* __restrict__ w, const float* __restrict__ u,
    float* __restrict__ rt, float* __restrict__ kt,
    float* __restrict__ aL, float* __restrict__ pdiag,
    int B, int T, int C, int H, int L) {
  __shared__ float pls[64 * 65];
  int nch = T / L;
  int blk = blockIdx.x;
  int bh = blk / nch, c = blk - bh * nch;
  int b = bh / H, h = bh - b * H;
  int j = threadIdx.x;
  float uj = u[h * 64 + j];
  float cum = 0.f;
  long base = ((long)b * T + (long)c * L) * C + h * 64 + j;
  for (int tau = 0; tau < L; tau++) {
    long off = base + (long)tau * C;
    float wv = w[off];
    float rv = r[off];
    float kv = k[off];
    float e = expf(wv);
    rt[off] = rv * expf(-cum);
    cum += e;
    kt[off] = kv * expf(cum);
    pls[tau * 65 + j] = rv * uj * kv;
  }
  aL[((long)bh * nch + c) * 64 + j] = expf(-cum);
  __syncthreads();
  float s0 = 0.f, s1 = 0.f, s2 = 0.f, s3 = 0.f;
#pragma unroll
  for (int q = 0; q < 16; q++) {
    float4 p4 = *(const float4*)(pls + j * 65 + q * 4);
    s0 += p4.x; s1 += p4.y; s2 += p4.z; s3 += p4.w;
  }
  pdiag[(long)bh * T + c * L + j] = (s0 + s1) + (s2 + s3);
}

// --------------------------------------- chunked WKV: per-chunk KV outer ---
__global__ __launch_bounds__(256) void k_wkv_kv(
    const float* __restrict__ kt, const float* __restrict__ v,
    float* __restrict__ kvb, int B, int T, int C, int H, int L) {
  int nch = T / L;
  int blk = blockIdx.x;
  int bh = blk / nch, c = blk - bh * nch;
  int b = bh / H, h = bh - b * H;
  __shared__ float Ks[64 * 64];
  __shared__ float Vs[64 * 64];
  int tid = threadIdx.x;
  int lane = tid & 63, jg = tid >> 6;
  long cbase = ((long)b * T + (long)c * L) * C + h * 64;
#pragma unroll
  for (int i = 0; i < 4; i++) {
    int chunk = jg * 4 + i;
    int row = chunk * 4 + (lane >> 4);
    int cq = lane & 15;
    GLDS16(kt + cbase + (long)row * C + cq * 4, Ks + chunk * 256);
    GLDS16(v + cbase + (long)row * C + cq * 4, Vs + chunk * 256);
  }
  __syncthreads();
  float acc[16];
#pragma unroll
  for (int q = 0; q < 16; q++) acc[q] = 0.f;
  for (int s = 0; s < 64; s++) {
    float vi = Vs[s * 64 + lane];
#pragma unroll
    for (int q4 = 0; q4 < 4; q4++) {
      float4 kk = *(const float4*)(Ks + s * 64 + jg * 16 + q4 * 4);
      acc[q4 * 4 + 0] = fmaf(kk.x, vi, acc[q4 * 4 + 0]);
      acc[q4 * 4 + 1] = fmaf(kk.y, vi, acc[q4 * 4 + 1]);
      acc[q4 * 4 + 2] = fmaf(kk.z, vi, acc[q4 * 4 + 2]);
      acc[q4 * 4 + 3] = fmaf(kk.w, vi, acc[q4 * 4 + 3]);
    }
  }
  float* out = kvb + ((long)bh * nch + c) * 4096;
#pragma unroll
  for (int q = 0; q < 16; q++) out[(jg * 16 + q) * 64 + lane] = acc[q];
}

// ---------------------------------------- chunked WKV: state prefix scan ---
__global__ __launch_bounds__(256) void k_wkv_scan(
    const float* __restrict__ kvb, const float* __restrict__ aL,
    float* __restrict__ Scb, int nch) {
  int bh = blockIdx.x >> 4;
  int e = ((blockIdx.x & 15) << 8) + threadIdx.x;   // 0..4095
  float S = 0.f;
  for (int c = 0; c < nch; c++) {
    long cb = ((long)bh * nch + c) * 4096 + e;
    Scb[cb] = S;
    S = aL[((long)bh * nch + c) * 64 + (e >> 6)] * (S + kvb[cb]);
  }
}

// ------------- chunked WKV: intra + inter + groupnorm*gate (fused) ---------
__global__ __launch_bounds__(256, 4) void k_wkv_intra(
    const float* __restrict__ rt, const float* __restrict__ kt,
    const float* __restrict__ v, const float* __restrict__ pdiag,
    const float* __restrict__ Scb, const float* __restrict__ g,
    const float* __restrict__ ln_w, const float* __restrict__ ln_b,
    ushort* __restrict__ z, int B, int T, int C, int H, int L) {
  int nch = T / L;
  int blk = blockIdx.x;
  int bh = blk / nch, c = blk - bh * nch;
  int b = bh / H, h = bh - b * H;
  __shared__ float TA[64 * 64];
  __shared__ float TB[64 * 64];
  int tid = threadIdx.x;
  int lane = tid & 63, wid = tid >> 6;
  int tau = lane;
  long cbase = ((long)b * T + (long)c * L) * C + h * 64;
  const float* scp = Scb + ((long)bh * nch + c) * 4096;

  // --- stage: Rt (swizzled source) -> TA, Kt -> TB ---
#pragma unroll
  for (int i = 0; i < 4; i++) {
    int chunk = wid * 4 + i;
    int row = chunk * 4 + (lane >> 4);
    int cq = lane & 15;
    GLDS16(rt + cbase + (long)row * C + ((cq ^ (row & 15)) * 4),
           TA + chunk * 256);
    GLDS16(kt + cbase + (long)row * C + cq * 4, TB + chunk * 256);
  }
  __syncthreads();   // Rt+Kt resident (barrier drains vmcnt)

  // --- rreg: full Rt row per lane, via the inverse swizzle (4-way, cheap) --
  float4 rreg[16];
#pragma unroll
  for (int q = 0; q < 16; q++)
    rreg[q] = *(const float4*)(TA + tau * 64 + ((q ^ (tau & 15)) * 4));
  float pd = pdiag[(long)bh * T + c * L + tau];
  __syncthreads();   // all rreg reads done; TA reusable

  // --- stage V -> TA (lands during phase 1) ---
#pragma unroll
  for (int i = 0; i < 4; i++) {
    int chunk = wid * 4 + i;
    int row = chunk * 4 + (lane >> 4);
    GLDS16(v + cbase + (long)row * C + (lane & 15) * 4, TA + chunk * 256);
  }

  // --- phase 1: P^T row s over Kt row s (wave-own rows 16*wid..16*wid+15) --
#pragma unroll 2
  for (int ss = 0; ss < 16; ss++) {
    int s = wid * 16 + ss;
    float a0 = 0.f, a1 = 0.f, a2 = 0.f, a3 = 0.f;
#pragma unroll
    for (int q = 0; q < 16; q++) {
      float4 kk = *(const float4*)(TB + s * 64 + q * 4);   // broadcast
      a0 = fmaf(rreg[q].x, kk.x, a0);
      a1 = fmaf(rreg[q].y, kk.y, a1);
      a2 = fmaf(rreg[q].z, kk.z, a2);
      a3 = fmaf(rreg[q].w, kk.w, a3);
    }
    float a = (a0 + a1) + (a2 + a3);
    float val = (s < tau) ? a : (s == tau ? pd : 0.f);
    TB[s * 64 + tau] = val;
  }
  __syncthreads();   // P^T complete everywhere; V resident

  // --- pass A: acc += P^T ⊗ V ---
  int row0 = wid * 16 + ((lane >> 4) << 2);   // 4 consecutive output rows
  int c0 = (lane & 15) * 4;                   // 4 consecutive channels
  float4 acc0 = {0.f, 0.f, 0.f, 0.f};
  float4 acc1 = {0.f, 0.f, 0.f, 0.f};
  float4 acc2 = {0.f, 0.f, 0.f, 0.f};
  float4 acc3 = {0.f, 0.f, 0.f, 0.f};
#define FMA1(A, P, V4)                 \
  A.x = fmaf(P, V4.x, A.x);            \
  A.y = fmaf(P, V4.y, A.y);            \
  A.z = fmaf(P, V4.z, A.z);            \
  A.w = fmaf(P, V4.w, A.w);
#pragma unroll 4
  for (int j = 0; j < 64; j++) {
    float4 pp = *(const float4*)(TB + j * 64 + row0);   // 16-lane multicast
    float4 vv = *(const float4*)(TA + j * 64 + c0);     // 2-way (free)
    FMA1(acc0, pp.x, vv);
    FMA1(acc1, pp.y, vv);
    FMA1(acc2, pp.z, vv);
    FMA1(acc3, pp.w, vv);
  }
  __syncthreads();   // V reads done; TA reusable

  // --- Rt^T -> TA (wave wid owns q-rows [16*wid, 16*wid+16)) ---
#define WRQ(SG)                                                          \
  {                                                                      \
    _Pragma("unroll") for (int qq = 0; qq < 16; qq++) {                  \
      const float* rp = (const float*)&rreg[(SG) * 4 + (qq >> 2)];       \
      TA[((SG) * 16 + qq) * 64 + tau] = rp[qq & 3];                      \
    }                                                                    \
  }
  if (wid == 0)      WRQ(0)
  else if (wid == 1) WRQ(1)
  else if (wid == 2) WRQ(2)
  else               WRQ(3)
#undef WRQ
  __syncthreads();

  // --- pass B: acc += Rt^T ⊗ S_prev (S from global, coalesced, L1 x4) ---
#pragma unroll 4
  for (int j = 0; j < 64; j++) {
    float4 rr = *(const float4*)(TA + j * 64 + row0);   // 16-lane multicast
    float4 ssv = *(const float4*)(scp + j * 64 + c0);
    FMA1(acc0, rr.x, ssv);
    FMA1(acc1, rr.y, ssv);
    FMA1(acc2, rr.z, ssv);
    FMA1(acc3, rr.w, ssv);
  }
#undef FMA1

  // ---- fused groupnorm (per row over this head's 64 channels) * gate ----
  float4 lw4 = *(const float4*)(ln_w + h * 64 + c0);
  float4 lb4 = *(const float4*)(ln_b + h * 64 + c0);
#define GNROW(A, m)                                                        \
  {                                                                        \
    float s1 = (A.x + A.y) + (A.z + A.w);                                  \
    s1 += __shfl_xor(s1, 1, 64);                                           \
    s1 += __shfl_xor(s1, 2, 64);                                           \
    s1 += __shfl_xor(s1, 4, 64);                                           \
    s1 += __shfl_xor(s1, 8, 64);                                           \
    float mu = s1 * (1.f / 64.f);                                          \
    float4 dd;                                                             \
    dd.x = A.x - mu; dd.y = A.y - mu; dd.z = A.z - mu; dd.w = A.w - mu;    \
    float s2 = (dd.x * dd.x + dd.y * dd.y) + (dd.z * dd.z + dd.w * dd.w);  \
    s2 += __shfl_xor(s2, 1, 64);                                           \
    s2 += __shfl_xor(s2, 2, 64);                                           \
    s2 += __shfl_xor(s2, 4, 64);                                           \
    s2 += __shfl_xor(s2, 8, 64);                                           \
    float rstd = rsqrtf(s2 * (1.f / 64.f) + 1e-5f);                        \
    long off = cbase + (long)(row0 + m) * C + c0;                          \
    float4 g4 = *(const float4*)(g + off);                                 \
    ushort4 ob;                                                            \
    ob.x = f2bf((dd.x * rstd * lw4.x + lb4.x) * g4.x);                     \
    ob.y = f2bf((dd.y * rstd * lw4.y + lb4.y) * g4.y);                     \
    ob.z = f2bf((dd.z * rstd * lw4.z + lb4.z) * g4.z);                     \
    ob.w = f2bf((dd.w * rstd * lw4.w + lb4.w) * g4.w);                     \
    *(ushort4*)(z + off) = ob;                                             \
  }
  GNROW(acc0, 0)
  GNROW(acc1, 1)
  GNROW(acc2, 2)
  GNROW(acc3, 3)
#undef GNROW
}

// ---------------------------------------------------------------- launch ---
extern "C" void kernel_launch(void* const* d_in, const int* in_sizes, int n_in,
                              void* d_out, int out_size, void* d_ws, size_t ws_size,
                              hipStream_t stream) {
  const int B = 8, T = 1024, C = 768, H = 12, ph = 32, pw = 32;
  const int M = B * T;
  const int L = 64, NCH = T / L;

  const float* x        = (const float*)d_in[0];
  const float* W_r      = (const float*)d_in[1];
  const float* W_k      = (const float*)d_in[2];
  const float* W_v      = (const float*)d_in[3];
  const float* W_g      = (const float*)d_in[4];
  const float* W_o      = (const float*)d_in[5];
  const float* maa_x    = (const float*)d_in[6];
  const float* maa_w    = (const float*)d_in[7];
  const float* maa_k    = (const float*)d_in[8];
  const float* maa_v    = (const float*)d_in[9];
  const float* maa_r    = (const float*)d_in[10];
  const float* maa_g    = (const float*)d_in[11];
  const float* maa_w1   = (const float*)d_in[12];
  const float* maa_w2   = (const float*)d_in[13];
  const float* time_dec = (const float*)d_in[14];
  const float* dec_w1   = (const float*)d_in[15];
  const float* dec_w2   = (const float*)d_in[16];
  const float* faaaa    = (const float*)d_in[17];
  const float* ln_w     = (const float*)d_in[18];
  const float* ln_b     = (const float*)d_in[19];

  float* ws = (float*)d_ws;
  const size_t S = (size_t)M * C;
  float* F0 = ws + 0 * S;   // xx -> r -> kvb
  float* F1 = ws + 1 * S;   // xxx_bf -> k -> Scb
  float* F2 = ws + 2 * S;   // xw_bf -> w -> Kt (in place)
  float* F3 = ws + 3 * S;   // v
  float* F4 = ws + 4 * S;   // g
  float* F5 = ws + 5 * S;   // xr_bf | xk_bf -> Rt (fp32)
  float* F6 = ws + 6 * S;   // xv_bf | xg_bf -> z_bf
  float* t5    = ws + 7 * S;            // [M,160] bf16 t5b -> bf16 W_r..W_g
  float* t6    = t5 + (size_t)M * 160;  // bf16 W_o + maa1T + decT
  float* aLb   = t6 + (size_t)M * 64;
  float* pdiag = aLb + (size_t)B * H * NCH * 64;
  float* dec_t = pdiag + (size_t)B * H * T;   // [M,64] t_bf + w2T scratch

  ushort* xxx_bf = (ushort*)F1;
  ushort* xw_bf = (ushort*)F2;
  ushort* xr_bf = (ushort*)F5;
  ushort* xk_bf = xr_bf + S;
  ushort* xv_bf = (ushort*)F6;
  ushort* xg_bf = xv_bf + S;
  ushort* z_bf  = (ushort*)F6;
  ushort* t5b   = (ushort*)t5;          // [M,160] bf16
  ushort* t_bf  = (ushort*)dec_t;       // [M,64] bf16
  ushort* w2T   = t_bf + (size_t)M * 64;  // [768,160] bf16 (dead after mix5)
  float* kvb = F0;
  float* Scb = F1;
  const int WSZ = C * C;
  ushort* wr_bf = (ushort*)t5;
  ushort* wk_bf = wr_bf + WSZ;
  ushort* wv_bf = wk_bf + WSZ;
  ushort* wg_bf = wv_bf + WSZ;
  ushort* wo_bf = (ushort*)t6;
  ushort* maa1T = wo_bf + WSZ;          // [256,768]
  ushort* w1dT  = maa1T + 256 * 768;    // [128,768]
  ushort* w2dT  = w1dT + 128 * 768;     // [768,64]

  // 1. qshift (xx fp32, xxx bf16)
  {
    long total = (long)M * C;
    k_qshift<<<(int)((total + 255) / 256), 256, 0, stream>>>(
        x, maa_x, F0, xxx_bf, B, T, C, ph, pw);
  }
  // 2. weight transposes -> bf16; t5b = tanh(xxx @ maa_w1) via MFMA (bf16)
  {
    dim3 gt(3, 256);
    k_w1t<<<gt, 256, 0, stream>>>(maa_w1, maa1T);
    k_w2t<<<768 * 160 / 256, 256, 0, stream>>>(maa_w2, w2T);
    k_decT<<<(128 * 768 + 768 * 64) / 256, 256, 0, stream>>>(
        dec_w1, dec_w2, w1dT, w2dT);
    dim3 grid(2, M / 128);
    k_gemm_bf<EPI_TANH, true, true><<<grid, 256, 0, stream>>>(
        xxx_bf, maa1T, nullptr, t5b, M, 160, C);
  }
  // 3. mix5 on MFMA (all outputs bf16)
  {
    dim3 grid(C / 128, M / 64);
    k_mix5m<<<grid, 256, 0, stream>>>(t5b, w2T, x, F0, maa_w, maa_k, maa_v,
                                      maa_r, maa_g, xw_bf, xk_bf, xv_bf, xr_bf,
                                      xg_bf, C);
  }
  // 4. weight conversion (t5b data dead now)
  {
    dim3 grid((WSZ / 4 + 255) / 256, 5);
    k_cvt5<<<grid, 256, 0, stream>>>(W_r, W_k, W_v, W_g, W_o,
                                     wr_bf, wk_bf, wv_bf, wg_bf, wo_bf, WSZ);
  }
  // 5. big projections: ONE batched bf16 MFMA dispatch (1536 blocks, 1D)
  {
    k_proj4<<<(C / 128) * (M / 128) * 4, 256, 0, stream>>>(
        xr_bf, xk_bf, xv_bf, xg_bf, wr_bf, wk_bf, wv_bf, wg_bf,
        F0, F1, F3, F4, M, C, C);
  }
  // 6. decay path on MFMA
  {
    dim3 g1(1, M / 128);
    k_gemm_bf<EPI_TANH, true, true><<<g1, 256, 0, stream>>>(
        xw_bf, w1dT, nullptr, t_bf, M, 64, C);
    dim3 g2(C / 128, M / 128);
    k_gemm_bf<EPI_BIAS, false, false><<<g2, 256, 0, stream>>>(
        t_bf, w2dT, time_dec, F2, M, C, 64);
  }
  // 7. chunked wkv6: pre -> kv -> scan -> intra(+GN+gate -> z bf16)
  k_wkv_pre<<<B * H * NCH, 64, 0, stream>>>(F0, F1, F2, faaaa, F5, F2,
                                            aLb, pdiag, B, T, C, H, L);
  k_wkv_kv<<<B * H * NCH, 256, 0, stream>>>(F2, F3, kvb, B, T, C, H, L);
  k_wkv_scan<<<B * H * 16, 256, 0, stream>>>(kvb, aLb, Scb, NCH);
  k_wkv_intra<<<B * H * NCH, 256, 0, stream>>>(F5, F2, F3, pdiag, Scb, F4,
                                               ln_w, ln_b, z_bf, B, T, C, H, L);
  // 8. out = z @ W_o^T (bf16 MFMA)
  {
    dim3 grid(C / 128, M / 128);
    k_gemm_bf<EPI_NONE, false, false><<<grid, 256, 0, stream>>>(
        z_bf, wo_bf, nullptr, (float*)d_out, M, C, C);
  }
}

// Round 5
// 417.097 us; speedup vs baseline: 1.2884x; 1.0596x over previous
//
#include <hip/hip_runtime.h>
#include <math.h>

// ---------------------------------------------------------------------------
// TimeMix (RWKV-6 vision block) — round 14: intra occupancy 4->5 blocks/CU +
// setprio; xx round-trip eliminated (mix5m recomputes shift inline, -50MB);
// weight transposes fused into one k_wprep launch. B=8, T=1024, C=768, H=12.
// ---------------------------------------------------------------------------

#define EPI_NONE 0
#define EPI_TANH 1
#define EPI_RELU 2
#define EPI_BIAS 3

typedef float f32x4 __attribute__((ext_vector_type(4)));
typedef __bf16 bf16x8 __attribute__((ext_vector_type(8)));

__device__ __forceinline__ ushort f2bf(float x) {
  unsigned u = __float_as_uint(x);
  return (ushort)((u + 0x7fffu + ((u >> 16) & 1u)) >> 16);
}

#define GLDS16(gp, lp)                                                   \
  __builtin_amdgcn_global_load_lds(                                      \
      (const __attribute__((address_space(1))) void*)(gp),               \
      (__attribute__((address_space(3))) void*)(lp), 16, 0, 0)

// ---------------------------------------------------------------- qshift ---
// xx no longer materialized (mix5m recomputes it); only xxx_bf written.
__global__ __launch_bounds__(256) void k_qshift(
    const float* __restrict__ x, const float* __restrict__ maa_x,
    ushort* __restrict__ xxx_bf,
    int B, int T, int C, int ph, int pw) {
  long idx = (long)blockIdx.x * blockDim.x + threadIdx.x;
  long total = (long)B * T * C;
  if (idx >= total) return;
  int c = (int)(idx % C);
  long bt = idx / C;
  int t = (int)(bt % T);
  int quarter = (c & 63) >> 4;
  int hh = t / pw;
  int ww = t - hh * pw;
  long rowbase = (bt - t) * C;
  float sval = 0.f;
  int st = -1;
  if (quarter == 0)      { if (ww >= 1)      st = t - 1;  }
  else if (quarter == 1) { if (ww < pw - 1)  st = t + 1;  }
  else if (quarter == 2) { if (hh >= 1)      st = t - pw; }
  else                   { if (hh < ph - 1)  st = t + pw; }
  if (st >= 0) sval = x[rowbase + (long)st * C + c];
  float xval = x[idx];
  float d = sval - xval;
  xxx_bf[idx] = f2bf(xval + d * maa_x[c]);
}

// ----------------- fused weight transposes -> bf16 (one launch) ------------
// maa1T [256][768] | w2T [768][160] | w1dT [128][768] | w2dT [768][64]
__global__ __launch_bounds__(256) void k_wprep(
    const float* __restrict__ w1, const float* __restrict__ w2,
    const float* __restrict__ dw1, const float* __restrict__ dw2,
    ushort* __restrict__ maa1T, ushort* __restrict__ w2T,
    ushort* __restrict__ w1dT, ushort* __restrict__ w2dT) {
  int idx = blockIdx.x * 256 + threadIdx.x;
  if (idx < 196608) {
    int n = idx / 768, k = idx - n * 768;
    maa1T[idx] = f2bf(n < 160 ? w1[(size_t)k * 160 + n] : 0.f);
  } else if (idx < 196608 + 122880) {
    int j = idx - 196608;
    int c = j / 160, kk = j - c * 160;
    w2T[j] = f2bf(w2[(size_t)kk * 768 + c]);
  } else if (idx < 196608 + 122880 + 98304) {
    int j = idx - (196608 + 122880);
    int n = j / 768, k = j - n * 768;
    w1dT[j] = f2bf(n < 64 ? dw1[(size_t)k * 64 + n] : 0.f);
  } else {
    int j = idx - (196608 + 122880 + 98304);
    int n = j >> 6, k = j & 63;
    w2dT[j] = f2bf(dw2[(size_t)k * 768 + n]);
  }
}

// --------------------------- mix5 on MFMA, no LDS, no barriers -------------
// dh recomputed inline from x (quarter = j&3 is wave-uniform; shifted row is
// mr+/-1 or mr+/-pw). Saves the xx fp32 round-trip entirely.
__global__ __launch_bounds__(256) void k_mix5m(
    const ushort* __restrict__ t5b, const ushort* __restrict__ w2T,
    const float* __restrict__ x,
    const float* __restrict__ maa_w, const float* __restrict__ maa_k,
    const float* __restrict__ maa_v, const float* __restrict__ maa_r,
    const float* __restrict__ maa_g,
    ushort* __restrict__ xw, ushort* __restrict__ xk, ushort* __restrict__ xvb,
    ushort* __restrict__ xr, ushort* __restrict__ xg,
    int C, int T, int ph, int pw) {
  int tid = threadIdx.x;
  int lane = tid & 63, wid = tid >> 6;
  int m0 = blockIdx.y * 64, n0 = blockIdx.x * 128;
  int lm = lane & 15, lk = (lane >> 4) * 8;
  int rq = (lane >> 4) * 4;
  const ushort* ap = t5b + (size_t)(m0 + wid * 16 + lm) * 160 + lk;

  // shifted-row table per (q, quarter): absolute source row or -1
  int stq[4][4];
#pragma unroll
  for (int q = 0; q < 4; q++) {
    int mr = m0 + wid * 16 + rq + q;
    int t = mr % T;
    int hh = t / pw, ww = t - hh * pw;
    stq[q][0] = (ww >= 1)      ? mr - 1  : -1;
    stq[q][1] = (ww < pw - 1)  ? mr + 1  : -1;
    stq[q][2] = (hh >= 1)      ? mr - pw : -1;
    stq[q][3] = (hh < ph - 1)  ? mr + pw : -1;
  }

  float xh[8][4], dh[8][4];
#pragma unroll
  for (int j = 0; j < 8; j++)
#pragma unroll
    for (int q = 0; q < 4; q++) {
      int mr = m0 + wid * 16 + rq + q;
      int col = n0 + j * 16 + lm;
      float xv = x[(size_t)mr * C + col];
      int sr = stq[q][j & 3];
      float sv = (sr >= 0) ? x[(size_t)sr * C + col] : 0.f;
      xh[j][q] = xv;
      dh[j][q] = sv - xv;
    }

#pragma unroll
  for (int f = 0; f < 5; f++) {
    bf16x8 af = *(const bf16x8*)(ap + f * 32);
    f32x4 acc[8];
#pragma unroll
    for (int j = 0; j < 8; j++) {
      bf16x8 bfj = *(const bf16x8*)(w2T +
          (size_t)(n0 + j * 16 + lm) * 160 + f * 32 + lk);
      acc[j] = __builtin_amdgcn_mfma_f32_16x16x32_bf16(
          af, bfj, (f32x4){0.f, 0.f, 0.f, 0.f}, 0, 0, 0);
    }
    const float* maa_f = (f == 0) ? maa_w : (f == 1) ? maa_k
                        : (f == 2) ? maa_v : (f == 3) ? maa_r : maa_g;
    ushort* dst = (f == 0) ? xw : (f == 1) ? xk
                 : (f == 2) ? xvb : (f == 3) ? xr : xg;
#pragma unroll
    for (int j = 0; j < 8; j++) {
      float mf = maa_f[n0 + j * 16 + lm];
#pragma unroll
      for (int q = 0; q < 4; q++) {
        size_t off = (size_t)(m0 + wid * 16 + rq + q) * C + (n0 + j * 16 + lm);
        dst[off] = f2bf(xh[j][q] + dh[j][q] * (mf + acc[j][q]));
      }
    }
  }
}

// -------------------------------------------- fp32 -> bf16 cvt (5 arrays) --
__global__ __launch_bounds__(256) void k_cvt5(
    const float* __restrict__ s0, const float* __restrict__ s1,
    const float* __restrict__ s2, const float* __restrict__ s3,
    const float* __restrict__ s4,
    ushort* __restrict__ d0, ushort* __restrict__ d1,
    ushort* __restrict__ d2, ushort* __restrict__ d3,
    ushort* __restrict__ d4, int n) {
  const float* s;
  ushort* d;
  switch (blockIdx.y) {
    case 0: s = s0; d = d0; break;
    case 1: s = s1; d = d1; break;
    case 2: s = s2; d = d2; break;
    case 3: s = s3; d = d3; break;
    default: s = s4; d = d4; break;
  }
  int i = (blockIdx.x * 256 + threadIdx.x) * 4;
  if (i >= n) return;
  float4 v = *(const float4*)(s + i);
  ushort4 o;
  o.x = f2bf(v.x); o.y = f2bf(v.y); o.z = f2bf(v.z); o.w = f2bf(v.w);
  *(ushort4*)(d + i) = o;
}

// ----------------------------------------------------- bf16 MFMA GEMM ------
// BK=64 + XOR chunk swizzle (bank-conflict-free) + XCD block swizzle.
template <int EPI, bool NMASK, bool OBF16>
__global__ __launch_bounds__(256) void k_gemm_bf(
    const ushort* __restrict__ A, const ushort* __restrict__ W,
    const float* __restrict__ bias, void* __restrict__ Cm,
    int M, int N, int K) {
  __shared__ ushort Al[128 * 64];
  __shared__ ushort Bl[128 * 64];
  int nwg = gridDim.x * gridDim.y;
  int bid = blockIdx.y * gridDim.x + blockIdx.x;
  int swz = (nwg & 7) == 0 ? ((bid & 7) * (nwg >> 3) + (bid >> 3)) : bid;
  int bx = swz % gridDim.x, by = swz / gridDim.x;
  int m0 = by * 128, n0 = bx * 128;
  int tid = threadIdx.x;
  int lane = tid & 63, wave = tid >> 6;
  int wm = (wave >> 1) * 64, wn = (wave & 1) * 64;
  int lm = lane & 15, g = lane >> 4;
  f32x4 acc[4][4];
#pragma unroll
  for (int i = 0; i < 4; i++)
#pragma unroll
    for (int j = 0; j < 4; j++) acc[i][j] = (f32x4){0.f, 0.f, 0.f, 0.f};

  for (int k0 = 0; k0 < K; k0 += 64) {
#pragma unroll
    for (int i = 0; i < 4; i++) {
      int cid = tid + i * 256;             // 0..1023 16B-chunks
      int row = cid >> 3, p = cid & 7;
      int cq = p ^ (row & 7);
      GLDS16(A + (size_t)(m0 + row) * K + k0 + cq * 8, Al + cid * 8);
      GLDS16(W + (size_t)(n0 + row) * K + k0 + cq * 8, Bl + cid * 8);
    }
    __syncthreads();
#pragma unroll
    for (int s = 0; s < 2; s++) {
      bf16x8 af[4], bf[4];
#pragma unroll
      for (int i = 0; i < 4; i++) {
        int r = wm + i * 16 + lm;
        af[i] = *(const bf16x8*)&Al[r * 64 + (((s * 4 + g) ^ (r & 7)) * 8)];
        int rb = wn + i * 16 + lm;
        bf[i] = *(const bf16x8*)&Bl[rb * 64 + (((s * 4 + g) ^ (rb & 7)) * 8)];
      }
#pragma unroll
      for (int i = 0; i < 4; i++)
#pragma unroll
        for (int j = 0; j < 4; j++)
          acc[i][j] = __builtin_amdgcn_mfma_f32_16x16x32_bf16(
              af[i], bf[j], acc[i][j], 0, 0, 0);
    }
    __syncthreads();
  }
  int rq = (lane >> 4) * 4;
#pragma unroll
  for (int i = 0; i < 4; i++) {
#pragma unroll
    for (int j = 0; j < 4; j++) {
      int gn = n0 + wn + j * 16 + lm;
      if (NMASK && gn >= N) continue;
      float bv = (EPI == EPI_BIAS) ? bias[gn] : 0.f;
#pragma unroll
      for (int q = 0; q < 4; q++) {
        int gm = m0 + wm + i * 16 + rq + q;
        float val = acc[i][j][q];
        if (EPI == EPI_BIAS) val += bv;
        if (EPI == EPI_RELU) val = fmaxf(val, 0.f);
        if (EPI == EPI_TANH) val = tanhf(val);
        if (OBF16) ((ushort*)Cm)[(size_t)gm * N + gn] = f2bf(val);
        else       ((float*)Cm)[(size_t)gm * N + gn] = val;
      }
    }
  }
}

// --------------------------------- batched 4-projection bf16 MFMA GEMM -----
__global__ __launch_bounds__(256) void k_proj4(
    const ushort* __restrict__ A0, const ushort* __restrict__ A1,
    const ushort* __restrict__ A2, const ushort* __restrict__ A3,
    const ushort* __restrict__ W0, const ushort* __restrict__ W1,
    const ushort* __restrict__ W2, const ushort* __restrict__ W3,
    float* __restrict__ C0, float* __restrict__ C1,
    float* __restrict__ C2, float* __restrict__ C3,
    int M, int N, int K) {
  int nwg = gridDim.x;                       // 1536, %8==0
  int bid = blockIdx.x;
  int swz = (bid & 7) * (nwg >> 3) + (bid >> 3);
  int nxt = N / 128;                         // 6
  int per_z = (M / 128) * nxt;               // 384
  int z = swz / per_z;
  int rem = swz - z * per_z;
  int my = rem / nxt, nx = rem - my * nxt;
  const ushort* A = (z == 0) ? A0 : (z == 1) ? A1 : (z == 2) ? A2 : A3;
  const ushort* W = (z == 0) ? W0 : (z == 1) ? W1 : (z == 2) ? W2 : W3;
  float* Cm       = (z == 0) ? C0 : (z == 1) ? C1 : (z == 2) ? C2 : C3;
  __shared__ ushort Al[128 * 64];
  __shared__ ushort Bl[128 * 64];
  int tid = threadIdx.x;
  int m0 = my * 128, n0 = nx * 128;
  int lane = tid & 63, wave = tid >> 6;
  int wm = (wave >> 1) * 64, wn = (wave & 1) * 64;
  int lm = lane & 15, g = lane >> 4;
  f32x4 acc[4][4];
#pragma unroll
  for (int i = 0; i < 4; i++)
#pragma unroll
    for (int j = 0; j < 4; j++) acc[i][j] = (f32x4){0.f, 0.f, 0.f, 0.f};

  for (int k0 = 0; k0 < K; k0 += 64) {
#pragma unroll
    for (int i = 0; i < 4; i++) {
      int cid = tid + i * 256;
      int row = cid >> 3, p = cid & 7;
      int cq = p ^ (row & 7);
      GLDS16(A + (size_t)(m0 + row) * K + k0 + cq * 8, Al + cid * 8);
      GLDS16(W + (size_t)(n0 + row) * K + k0 + cq * 8, Bl + cid * 8);
    }
    __syncthreads();
#pragma unroll
    for (int s = 0; s < 2; s++) {
      bf16x8 af[4], bf[4];
#pragma unroll
      for (int i = 0; i < 4; i++) {
        int r = wm + i * 16 + lm;
        af[i] = *(const bf16x8*)&Al[r * 64 + (((s * 4 + g) ^ (r & 7)) * 8)];
        int rb = wn + i * 16 + lm;
        bf[i] = *(const bf16x8*)&Bl[rb * 64 + (((s * 4 + g) ^ (rb & 7)) * 8)];
      }
#pragma unroll
      for (int i = 0; i < 4; i++)
#pragma unroll
        for (int j = 0; j < 4; j++)
          acc[i][j] = __builtin_amdgcn_mfma_f32_16x16x32_bf16(
              af[i], bf[j], acc[i][j], 0, 0, 0);
    }
    __syncthreads();
  }
  bool relu = (z == 3);
  int rq = (lane >> 4) * 4;
#pragma unroll
  for (int i = 0; i < 4; i++) {
#pragma unroll
    for (int j = 0; j < 4; j++) {
      int gn = n0 + wn + j * 16 + lm;
#pragma unroll
      for (int q = 0; q < 4; q++) {
        int gm = m0 + wm + i * 16 + rq + q;
        float val = acc[i][j][q];
        if (relu) val = fmaxf(val, 0.f);
        Cm[(size_t)gm * N + gn] = val;
      }
    }
  }
}

// ------------------------------------------------- chunked WKV: phase pre --
__global__ __launch_bounds__(64) void k_wkv_pre(
    const float* __restrict__ r, const float* __restrict__ k,
    const float* __restrict__ w, const float* __restrict__ u,
    float* __restrict__ rt, float* __restrict__ kt,
    float* __restrict__ aL, float* __restrict__ pdiag,
    int B, int T, int C, int H, int L) {
  __shared__ float pls[64 * 65];
  int nch = T / L;
  int blk = blockIdx.x;
  int bh = blk / nch, c = blk - bh * nch;
  int b = bh / H, h = bh - b * H;
  int j = threadIdx.x;
  float uj = u[h * 64 + j];
  float cum = 0.f;
  long base = ((long)b * T + (long)c * L) * C + h * 64 + j;
  for (int tau = 0; tau < L; tau++) {
    long off = base + (long)tau * C;
    float wv = w[off];
    float rv = r[off];
    float kv = k[off];
    float e = expf(wv);
    rt[off] = rv * expf(-cum);
    cum += e;
    kt[off] = kv * expf(cum);
    pls[tau * 65 + j] = rv * uj * kv;
  }
  aL[((long)bh * nch + c) * 64 + j] = expf(-cum);
  __syncthreads();
  float s0 = 0.f, s1 = 0.f, s2 = 0.f, s3 = 0.f;
#pragma unroll
  for (int q = 0; q < 16; q++) {
    float4 p4 = *(const float4*)(pls + j * 65 + q * 4);
    s0 += p4.x; s1 += p4.y; s2 += p4.z; s3 += p4.w;
  }
  pdiag[(long)bh * T + c * L + j] = (s0 + s1) + (s2 + s3);
}

// --------------------------------------- chunked WKV: per-chunk KV outer ---
__global__ __launch_bounds__(256) void k_wkv_kv(
    const float* __restrict__ kt, const float* __restrict__ v,
    float* __restrict__ kvb, int B, int T, int C, int H, int L) {
  int nch = T / L;
  int blk = blockIdx.x;
  int bh = blk / nch, c = blk - bh * nch;
  int b = bh / H, h = bh - b * H;
  __shared__ float Ks[64 * 64];
  __shared__ float Vs[64 * 64];
  int tid = threadIdx.x;
  int lane = tid & 63, jg = tid >> 6;
  long cbase = ((long)b * T + (long)c * L) * C + h * 64;
#pragma unroll
  for (int i = 0; i < 4; i++) {
    int chunk = jg * 4 + i;
    int row = chunk * 4 + (lane >> 4);
    int cq = lane & 15;
    GLDS16(kt + cbase + (long)row * C + cq * 4, Ks + chunk * 256);
    GLDS16(v + cbase + (long)row * C + cq * 4, Vs + chunk * 256);
  }
  __syncthreads();
  float acc[16];
#pragma unroll
  for (int q = 0; q < 16; q++) acc[q] = 0.f;
  for (int s = 0; s < 64; s++) {
    float vi = Vs[s * 64 + lane];
#pragma unroll
    for (int q4 = 0; q4 < 4; q4++) {
      float4 kk = *(const float4*)(Ks + s * 64 + jg * 16 + q4 * 4);
      acc[q4 * 4 + 0] = fmaf(kk.x, vi, acc[q4 * 4 + 0]);
      acc[q4 * 4 + 1] = fmaf(kk.y, vi, acc[q4 * 4 + 1]);
      acc[q4 * 4 + 2] = fmaf(kk.z, vi, acc[q4 * 4 + 2]);
      acc[q4 * 4 + 3] = fmaf(kk.w, vi, acc[q4 * 4 + 3]);
    }
  }
  float* out = kvb + ((long)bh * nch + c) * 4096;
#pragma unroll
  for (int q = 0; q < 16; q++) out[(jg * 16 + q) * 64 + lane] = acc[q];
}

// ---------------------------------------- chunked WKV: state prefix scan ---
__global__ __launch_bounds__(256) void k_wkv_scan(
    const float* __restrict__ kvb, const float* __restrict__ aL,
    float* __restrict__ Scb, int nch) {
  int bh = blockIdx.x >> 4;
  int e = ((blockIdx.x & 15) << 8) + threadIdx.x;   // 0..4095
  float S = 0.f;
  for (int c = 0; c < nch; c++) {
    long cb = ((long)bh * nch + c) * 4096 + e;
    Scb[cb] = S;
    S = aL[((long)bh * nch + c) * 64 + (e >> 6)] * (S + kvb[cb]);
  }
}

// ------------- chunked WKV: intra + inter + groupnorm*gate (fused) ---------
// 5 blocks/CU (5 x 32KB = exactly 160KiB); setprio(1) around compute phases.
__global__ __launch_bounds__(256, 5) void k_wkv_intra(
    const float* __restrict__ rt, const float* __restrict__ kt,
    const float* __restrict__ v, const float* __restrict__ pdiag,
    const float* __restrict__ Scb, const float* __restrict__ g,
    const float* __restrict__ ln_w, const float* __restrict__ ln_b,
    ushort* __restrict__ z, int B, int T, int C, int H, int L) {
  int nch = T / L;
  int blk = blockIdx.x;
  int bh = blk / nch, c = blk - bh * nch;
  int b = bh / H, h = bh - b * H;
  __shared__ float TA[64 * 64];
  __shared__ float TB[64 * 64];
  int tid = threadIdx.x;
  int lane = tid & 63, wid = tid >> 6;
  int tau = lane;
  long cbase = ((long)b * T + (long)c * L) * C + h * 64;
  const float* scp = Scb + ((long)bh * nch + c) * 4096;

  // --- stage: Rt (swizzled source) -> TA, Kt -> TB ---
#pragma unroll
  for (int i = 0; i < 4; i++) {
    int chunk = wid * 4 + i;
    int row = chunk * 4 + (lane >> 4);
    int cq = lane & 15;
    GLDS16(rt + cbase + (long)row * C + ((cq ^ (row & 15)) * 4),
           TA + chunk * 256);
    GLDS16(kt + cbase + (long)row * C + cq * 4, TB + chunk * 256);
  }
  __syncthreads();   // Rt+Kt resident (barrier drains vmcnt)

  // --- rreg: full Rt row per lane, via the inverse swizzle (4-way, cheap) --
  float4 rreg[16];
#pragma unroll
  for (int q = 0; q < 16; q++)
    rreg[q] = *(const float4*)(TA + tau * 64 + ((q ^ (tau & 15)) * 4));
  float pd = pdiag[(long)bh * T + c * L + tau];
  __syncthreads();   // all rreg reads done; TA reusable

  // --- stage V -> TA (lands during phase 1) ---
#pragma unroll
  for (int i = 0; i < 4; i++) {
    int chunk = wid * 4 + i;
    int row = chunk * 4 + (lane >> 4);
    GLDS16(v + cbase + (long)row * C + (lane & 15) * 4, TA + chunk * 256);
  }

  // --- phase 1: P^T row s over Kt row s (wave-own rows 16*wid..16*wid+15) --
  __builtin_amdgcn_s_setprio(1);
#pragma unroll 2
  for (int ss = 0; ss < 16; ss++) {
    int s = wid * 16 + ss;
    float a0 = 0.f, a1 = 0.f, a2 = 0.f, a3 = 0.f;
#pragma unroll
    for (int q = 0; q < 16; q++) {
      float4 kk = *(const float4*)(TB + s * 64 + q * 4);   // broadcast
      a0 = fmaf(rreg[q].x, kk.x, a0);
      a1 = fmaf(rreg[q].y, kk.y, a1);
      a2 = fmaf(rreg[q].z, kk.z, a2);
      a3 = fmaf(rreg[q].w, kk.w, a3);
    }
    float a = (a0 + a1) + (a2 + a3);
    float val = (s < tau) ? a : (s == tau ? pd : 0.f);
    TB[s * 64 + tau] = val;
  }
  __builtin_amdgcn_s_setprio(0);
  __syncthreads();   // P^T complete everywhere; V resident

  // --- pass A: acc += P^T ⊗ V ---
  int row0 = wid * 16 + ((lane >> 4) << 2);   // 4 consecutive output rows
  int c0 = (lane & 15) * 4;                   // 4 consecutive channels
  float4 acc0 = {0.f, 0.f, 0.f, 0.f};
  float4 acc1 = {0.f, 0.f, 0.f, 0.f};
  float4 acc2 = {0.f, 0.f, 0.f, 0.f};
  float4 acc3 = {0.f, 0.f, 0.f, 0.f};
#define FMA1(A, P, V4)                 \
  A.x = fmaf(P, V4.x, A.x);            \
  A.y = fmaf(P, V4.y, A.y);            \
  A.z = fmaf(P, V4.z, A.z);            \
  A.w = fmaf(P, V4.w, A.w);
  __builtin_amdgcn_s_setprio(1);
#pragma unroll 4
  for (int j = 0; j < 64; j++) {
    float4 pp = *(const float4*)(TB + j * 64 + row0);   // 16-lane multicast
    float4 vv = *(const float4*)(TA + j * 64 + c0);     // 2-way (free)
    FMA1(acc0, pp.x, vv);
    FMA1(acc1, pp.y, vv);
    FMA1(acc2, pp.z, vv);
    FMA1(acc3, pp.w, vv);
  }
  __builtin_amdgcn_s_setprio(0);
  __syncthreads();   // V reads done; TA reusable

  // --- Rt^T -> TA (wave wid owns q-rows [16*wid, 16*wid+16)) ---
#define WRQ(SG)                                                          \
  {                                                                      \
    _Pragma("unroll") for (int qq = 0; qq < 16; qq++) {                  \
      const float* rp = (const float*)&rreg[(SG) * 4 + (qq >> 2)];       \
      TA[((SG) * 16 + qq) * 64 + tau] = rp[qq & 3];                      \
    }                                                                    \
  }
  if (wid == 0)      WRQ(0)
  else if (wid == 1) WRQ(1)
  else if (wid == 2) WRQ(2)
  else               WRQ(3)
#undef WRQ
  __syncthreads();

  // --- pass B: acc += Rt^T ⊗ S_prev (S from global, coalesced, L1 x4) ---
  __builtin_amdgcn_s_setprio(1);
#pragma unroll 4
  for (int j = 0; j < 64; j++) {
    float4 rr = *(const float4*)(TA + j * 64 + row0);   // 16-lane multicast
    float4 ssv = *(const float4*)(scp + j * 64 + c0);
    FMA1(acc0, rr.x, ssv);
    FMA1(acc1, rr.y, ssv);
    FMA1(acc2, rr.z, ssv);
    FMA1(acc3, rr.w, ssv);
  }
  __builtin_amdgcn_s_setprio(0);
#undef FMA1

  // ---- fused groupnorm (per row over this head's 64 channels) * gate ----
  float4 lw4 = *(const float4*)(ln_w + h * 64 + c0);
  float4 lb4 = *(const float4*)(ln_b + h * 64 + c0);
#define GNROW(A, m)                                                        \
  {                                                                        \
    float s1 = (A.x + A.y) + (A.z + A.w);                                  \
    s1 += __shfl_xor(s1, 1, 64);                                           \
    s1 += __shfl_xor(s1, 2, 64);                                           \
    s1 += __shfl_xor(s1, 4, 64);                                           \
    s1 += __shfl_xor(s1, 8, 64);                                           \
    float mu = s1 * (1.f / 64.f);                                          \
    float4 dd;                                                             \
    dd.x = A.x - mu; dd.y = A.y - mu; dd.z = A.z - mu; dd.w = A.w - mu;    \
    float s2 = (dd.x * dd.x + dd.y * dd.y) + (dd.z * dd.z + dd.w * dd.w);  \
    s2 += __shfl_xor(s2, 1, 64);                                           \
    s2 += __shfl_xor(s2, 2, 64);                                           \
    s2 += __shfl_xor(s2, 4, 64);                                           \
    s2 += __shfl_xor(s2, 8, 64);                                           \
    float rstd = rsqrtf(s2 * (1.f / 64.f) + 1e-5f);                        \
    long off = cbase + (long)(row0 + m) * C + c0;                          \
    float4 g4 = *(const float4*)(g + off);                                 \
    ushort4 ob;                                                            \
    ob.x = f2bf((dd.x * rstd * lw4.x + lb4.x) * g4.x);                     \
    ob.y = f2bf((dd.y * rstd * lw4.y + lb4.y) * g4.y);                     \
    ob.z = f2bf((dd.z * rstd * lw4.z + lb4.z) * g4.z);                     \
    ob.w = f2bf((dd.w * rstd * lw4.w + lb4.w) * g4.w);                     \
    *(ushort4*)(z + off) = ob;                                             \
  }
  GNROW(acc0, 0)
  GNROW(acc1, 1)
  GNROW(acc2, 2)
  GNROW(acc3, 3)
#undef GNROW
}

// ---------------------------------------------------------------- launch ---
extern "C" void kernel_launch(void* const* d_in, const int* in_sizes, int n_in,
                              void* d_out, int out_size, void* d_ws, size_t ws_size,
                              hipStream_t stream) {
  const int B = 8, T = 1024, C = 768, H = 12, ph = 32, pw = 32;
  const int M = B * T;
  const int L = 64, NCH = T / L;

  const float* x        = (const float*)d_in[0];
  const float* W_r      = (const float*)d_in[1];
  const float* W_k      = (const float*)d_in[2];
  const float* W_v      = (const float*)d_in[3];
  const float* W_g      = (const float*)d_in[4];
  const float* W_o      = (const float*)d_in[5];
  const float* maa_x    = (const float*)d_in[6];
  const float* maa_w    = (const float*)d_in[7];
  const float* maa_k    = (const float*)d_in[8];
  const float* maa_v    = (const float*)d_in[9];
  const float* maa_r    = (const float*)d_in[10];
  const float* maa_g    = (const float*)d_in[11];
  const float* maa_w1   = (const float*)d_in[12];
  const float* maa_w2   = (const float*)d_in[13];
  const float* time_dec = (const float*)d_in[14];
  const float* dec_w1   = (const float*)d_in[15];
  const float* dec_w2   = (const float*)d_in[16];
  const float* faaaa    = (const float*)d_in[17];
  const float* ln_w     = (const float*)d_in[18];
  const float* ln_b     = (const float*)d_in[19];

  float* ws = (float*)d_ws;
  const size_t S = (size_t)M * C;
  float* F0 = ws + 0 * S;   // r -> kvb
  float* F1 = ws + 1 * S;   // xxx_bf -> k -> Scb
  float* F2 = ws + 2 * S;   // xw_bf -> w -> Kt (in place)
  float* F3 = ws + 3 * S;   // v
  float* F4 = ws + 4 * S;   // g
  float* F5 = ws + 5 * S;   // xr_bf | xk_bf -> Rt (fp32)
  float* F6 = ws + 6 * S;   // xv_bf | xg_bf -> z_bf
  float* t5    = ws + 7 * S;            // [M,160] bf16 t5b -> bf16 W_r..W_g
  float* t6    = t5 + (size_t)M * 160;  // bf16 W_o + maa1T + decT
  float* aLb   = t6 + (size_t)M * 64;
  float* pdiag = aLb + (size_t)B * H * NCH * 64;
  float* dec_t = pdiag + (size_t)B * H * T;   // [M,64] t_bf + w2T scratch

  ushort* xxx_bf = (ushort*)F1;
  ushort* xw_bf = (ushort*)F2;
  ushort* xr_bf = (ushort*)F5;
  ushort* xk_bf = xr_bf + S;
  ushort* xv_bf = (ushort*)F6;
  ushort* xg_bf = xv_bf + S;
  ushort* z_bf  = (ushort*)F6;
  ushort* t5b   = (ushort*)t5;          // [M,160] bf16
  ushort* t_bf  = (ushort*)dec_t;       // [M,64] bf16
  ushort* w2T   = t_bf + (size_t)M * 64;  // [768,160] bf16 (dead after mix5)
  float* kvb = F0;
  float* Scb = F1;
  const int WSZ = C * C;
  ushort* wr_bf = (ushort*)t5;
  ushort* wk_bf = wr_bf + WSZ;
  ushort* wv_bf = wk_bf + WSZ;
  ushort* wg_bf = wv_bf + WSZ;
  ushort* wo_bf = (ushort*)t6;
  ushort* maa1T = wo_bf + WSZ;          // [256,768]
  ushort* w1dT  = maa1T + 256 * 768;    // [128,768]
  ushort* w2dT  = w1dT + 128 * 768;     // [768,64]

  // 1. qshift (xxx bf16 only; xx recomputed in mix5m)
  {
    long total = (long)M * C;
    k_qshift<<<(int)((total + 255) / 256), 256, 0, stream>>>(
        x, maa_x, xxx_bf, B, T, C, ph, pw);
  }
  // 2. fused weight transposes -> bf16; t5b = tanh(xxx @ maa_w1) via MFMA
  {
    k_wprep<<<1824, 256, 0, stream>>>(maa_w1, maa_w2, dec_w1, dec_w2,
                                      maa1T, w2T, w1dT, w2dT);
    dim3 grid(2, M / 128);
    k_gemm_bf<EPI_TANH, true, true><<<grid, 256, 0, stream>>>(
        xxx_bf, maa1T, nullptr, t5b, M, 160, C);
  }
  // 3. mix5 on MFMA (all outputs bf16; dh inline)
  {
    dim3 grid(C / 128, M / 64);
    k_mix5m<<<grid, 256, 0, stream>>>(t5b, w2T, x, maa_w, maa_k, maa_v,
                                      maa_r, maa_g, xw_bf, xk_bf, xv_bf, xr_bf,
                                      xg_bf, C, T, ph, pw);
  }
  // 4. weight conversion (t5b data dead now)
  {
    dim3 grid((WSZ / 4 + 255) / 256, 5);
    k_cvt5<<<grid, 256, 0, stream>>>(W_r, W_k, W_v, W_g, W_o,
                                     wr_bf, wk_bf, wv_bf, wg_bf, wo_bf, WSZ);
  }
  // 5. big projections: ONE batched bf16 MFMA dispatch (1536 blocks, 1D)
  {
    k_proj4<<<(C / 128) * (M / 128) * 4, 256, 0, stream>>>(
        xr_bf, xk_bf, xv_bf, xg_bf, wr_bf, wk_bf, wv_bf, wg_bf,
        F0, F1, F3, F4, M, C, C);
  }
  // 6. decay path on MFMA
  {
    dim3 g1(1, M / 128);
    k_gemm_bf<EPI_TANH, true, true><<<g1, 256, 0, stream>>>(
        xw_bf, w1dT, nullptr, t_bf, M, 64, C);
    dim3 g2(C / 128, M / 128);
    k_gemm_bf<EPI_BIAS, false, false><<<g2, 256, 0, stream>>>(
        t_bf, w2dT, time_dec, F2, M, C, 64);
  }
  // 7. chunked wkv6: pre -> kv -> scan -> intra(+GN+gate -> z bf16)
  k_wkv_pre<<<B * H * NCH, 64, 0, stream>>>(F0, F1, F2, faaaa, F5, F2,
                                            aLb, pdiag, B, T, C, H, L);
  k_wkv_kv<<<B * H * NCH, 256, 0, stream>>>(F2, F3, kvb, B, T, C, H, L);
  k_wkv_scan<<<B * H * 16, 256, 0, stream>>>(kvb, aLb, Scb, NCH);
  k_wkv_intra<<<B * H * NCH, 256, 0, stream>>>(F5, F2, F3, pdiag, Scb, F4,
                                               ln_w, ln_b, z_bf, B, T, C, H, L);
  // 8. out = z @ W_o^T (bf16 MFMA)
  {
    dim3 grid(C / 128, M / 128);
    k_gemm_bf<EPI_NONE, false, false><<<grid, 256, 0, stream>>>(
        z_bf, wo_bf, nullptr, (float*)d_out, M, C, C);
  }
}